// Round 6
// baseline (6855.985 us; speedup 1.0000x reference)
//
#include <hip/hip_runtime.h>
#include <hip/hip_bf16.h>

#define B_ 2
#define T_ 1024
#define D_ 1024
#define H_ 16
#define DH_ 64
#define F_ 2048
#define E_ 8
#define M_ 2048   // B*T tokens

// ===== numpy-style pairwise sum of a[0..K), K in {1024, 2048}, one wave =====
template<bool ABS>
__device__ __forceinline__ float np_pairwise_wave(const float* a, int K, int lane) {
  int nb = K >> 7;
  float s = 0.f;
  if (lane < nb) {
    const float* p = a + (lane << 7);
    float r[8];
    #pragma unroll
    for (int j = 0; j < 8; ++j) r[j] = ABS ? fabsf(p[j]) : p[j];
    for (int i = 8; i < 128; i += 8)
      #pragma unroll
      for (int j = 0; j < 8; ++j) r[j] += ABS ? fabsf(p[i + j]) : p[i + j];
    s = ((r[0] + r[1]) + (r[2] + r[3])) + ((r[4] + r[5]) + (r[6] + r[7]));
  }
  for (int off = 1; off < nb; off <<= 1) s += __shfl_xor(s, off);
  return __shfl(s, 0);
}

// ===== row scale: f32 mean(|W|) pairwise, clipped at 1e-5 =====
__global__ __launch_bounds__(64) void k_scale(const float* __restrict__ W, int K,
                                              float* __restrict__ out) {
  int r = blockIdx.x, lane = threadIdx.x;
  float S = np_pairwise_wave<true>(W + (size_t)r * K, K, lane);
  if (lane == 0) {
    float m = S / (float)K;
    out[r] = fmaxf(m, 1e-5f);
  }
}

// ===== lambda = clip(expf(mean(lq)-mean(lk)), 0.1, 2.0) =====
__global__ __launch_bounds__(64) void k_lambda(const float* __restrict__ lq,
                                               const float* __restrict__ lk,
                                               float* __restrict__ lam) {
  int lane = threadIdx.x;
  float mq = np_pairwise_wave<false>(lq, 1024, lane) / 1024.0f;
  float mk = np_pairwise_wave<false>(lk, 1024, lane) / 1024.0f;
  if (lane == 0) {
    float l = expf(mq - mk);
    lam[0] = fminf(2.0f, fmaxf(0.1f, l));
  }
}

// ===== layernorm, f32 pairwise stats, in==out allowed =====
__global__ __launch_bounds__(256) void k_layernorm(const float* __restrict__ in,
                                                   const float* __restrict__ g,
                                                   const float* __restrict__ b,
                                                   float* __restrict__ out, int Dd) {
  #pragma clang fp contract(off)
  __shared__ float row[2048];
  __shared__ float sq[2048];
  __shared__ float stat[2];
  int m = blockIdx.x, tid = threadIdx.x;
  const float* src = in + (size_t)m * Dd;
  for (int d = tid; d < Dd; d += 256) row[d] = src[d];
  __syncthreads();
  if (tid < 64) {
    float S = np_pairwise_wave<false>(row, Dd, tid);
    if (tid == 0) stat[0] = S;
  }
  __syncthreads();
  float mean = stat[0] / (float)Dd;
  for (int d = tid; d < Dd; d += 256) { float t = row[d] - mean; sq[d] = t * t; }
  __syncthreads();
  if (tid < 64) {
    float S = np_pairwise_wave<false>(sq, Dd, tid);
    if (tid == 0) stat[1] = S;
  }
  __syncthreads();
  float var = stat[1] / (float)Dd;
  float rs = 1.0f / sqrtf(var + 1e-5f);
  float* dst = out + (size_t)m * Dd;
  for (int d = tid; d < Dd; d += 256) {
    float t = row[d] - mean;
    float u = t * rs;
    float v = u * g[d];
    dst[d] = v + b[d];
  }
}

// ===== f32 GEMM, fmaf chain, faithful f32 straight-through quant =====
// EPI: 0 store, 1 silu, 2 add residual, 4 routed conditional (topp/idx/eid)
template<int EPI>
__global__ __launch_bounds__(256) void k_gemm(const float* __restrict__ A, int lda,
    const float* __restrict__ W, const float* __restrict__ scf,
    float* __restrict__ Cout, int ldc, int K,
    const float* __restrict__ res,
    const int* __restrict__ idx, const float* __restrict__ topp, int eid)
{
  #pragma clang fp contract(off)
  int m0 = blockIdx.y * 128;
  int n0 = blockIdx.x * 128;

  __shared__ float As[16][128];
  __shared__ float Bs[16][128];
  int tid = threadIdx.x;
  int tx = tid & 15, ty = tid >> 4;
  int lm = tid >> 1;
  int lc = (tid & 1) * 8;

  const float* Arow = A + (size_t)(m0 + lm) * lda;
  const float* Wrow = W + (size_t)(n0 + lm) * K;
  float wscale = scf[n0 + lm];

  float acc[8][8];
  #pragma unroll
  for (int j = 0; j < 8; j++)
    #pragma unroll
    for (int i = 0; i < 8; i++) acc[j][i] = 0.f;

  for (int kt = 0; kt < K; kt += 16) {
    float4 a0 = *reinterpret_cast<const float4*>(Arow + kt + lc);
    float4 a1 = *reinterpret_cast<const float4*>(Arow + kt + lc + 4);
    As[lc + 0][lm] = a0.x; As[lc + 1][lm] = a0.y; As[lc + 2][lm] = a0.z; As[lc + 3][lm] = a0.w;
    As[lc + 4][lm] = a1.x; As[lc + 5][lm] = a1.y; As[lc + 6][lm] = a1.z; As[lc + 7][lm] = a1.w;
    float4 w0 = *reinterpret_cast<const float4*>(Wrow + kt + lc);
    float4 w1 = *reinterpret_cast<const float4*>(Wrow + kt + lc + 4);
    float wv[8] = {w0.x, w0.y, w0.z, w0.w, w1.x, w1.y, w1.z, w1.w};
    #pragma unroll
    for (int j = 0; j < 8; j++) {
      float q = rintf(wv[j] / wscale);
      q = fminf(1.f, fmaxf(-1.f, q));
      float aq = q * wscale;
      float t  = aq - wv[j];
      Bs[lc + j][lm] = wv[j] + t;
    }
    __syncthreads();
    #pragma unroll
    for (int k = 0; k < 16; k++) {
      float a[8], w[8];
      #pragma unroll
      for (int j = 0; j < 8; j++) a[j] = As[k][ty * 8 + j];
      #pragma unroll
      for (int i = 0; i < 8; i++) w[i] = Bs[k][tx * 8 + i];
      #pragma unroll
      for (int j = 0; j < 8; j++)
        #pragma unroll
        for (int i = 0; i < 8; i++) acc[j][i] = __builtin_fmaf(a[j], w[i], acc[j][i]);
    }
    __syncthreads();
  }

  #pragma unroll
  for (int j = 0; j < 8; j++) {
    int mrow = m0 + ty * 8 + j;
    float* crow = Cout + (size_t)mrow * ldc + n0;
    if (EPI == 4) {
      bool sel = (idx[mrow] == eid);
      if (sel) {
        float tp = topp[mrow];
        #pragma unroll
        for (int i = 0; i < 8; i++) crow[tx * 8 + i] = acc[j][i] * tp;
      } else if (eid == 0) {
        #pragma unroll
        for (int i = 0; i < 8; i++) crow[tx * 8 + i] = 0.f;
      }
    } else if (EPI == 2) {
      const float* rrow = res + (size_t)mrow * ldc + n0;
      #pragma unroll
      for (int i = 0; i < 8; i++) crow[tx * 8 + i] = rrow[tx * 8 + i] + acc[j][i];
    } else {
      #pragma unroll
      for (int i = 0; i < 8; i++) {
        float v = acc[j][i];
        if (EPI == 1) v = v * (1.0f / (1.0f + expf(-v)));
        crow[tx * 8 + i] = v;
      }
    }
  }
}

// ===== differential attention, REWRITTEN FROM SCRATCH (k_attn2) =====
// Direct global reads (no K/V LDS tiles). Block = (b,h) x 4 rows; warp w owns
// row t = 4*blockIdx.y + w. Scores via full-lane shuffles with clamped row
// pointer (no divergent shfl). Softmax per-element normalized. Serial-j PV.
__global__ __launch_bounds__(256) void k_attn2(const float* __restrict__ q,
                                               const float* __restrict__ kk,
                                               const float* __restrict__ vv,
                                               const float* __restrict__ lamp,
                                               float* __restrict__ out)
{
  #pragma clang fp contract(off)
  __shared__ float srow[4][2][1024];
  int bh = blockIdx.x;            // 0..31
  int b = bh >> 4, h = bh & 15;
  int w = threadIdx.x >> 6, lane = threadIdx.x & 63;
  int t = blockIdx.y * 4 + w;     // 0..1023
  size_t tokbase = (size_t)b * T_;
  float lam = lamp[0];

  const float* qrow = q + (tokbase + t) * 2048 + h * 64;
  float q1 = qrow[lane];
  float q2 = qrow[1024 + lane];

  // ---- scores s = (q . k_j) * DH^-0.5, lane handles j = jc + lane ----
  for (int jc = 0; jc <= t; jc += 64) {
    int j = jc + lane;
    int jcl = (j <= t) ? j : t;                 // clamp: keep all lanes active
    const float* krow = kk + (tokbase + jcl) * 2048 + h * 64;
    float s1 = 0.f, s2 = 0.f;
    #pragma unroll 8
    for (int dd = 0; dd < 64; ++dd) {
      s1 = __builtin_fmaf(__shfl(q1, dd), krow[dd], s1);
      s2 = __builtin_fmaf(__shfl(q2, dd), krow[1024 + dd], s2);
    }
    if (j <= t) {
      srow[w][0][j] = s1 * 0.125f;
      srow[w][1][j] = s2 * 0.125f;
    }
  }
  // srow[w] touched only by warp w -> no __syncthreads needed anywhere.

  // ---- dual softmax over j <= t ----
  float m1 = -1e30f, m2 = -1e30f;
  for (int j = lane; j <= t; j += 64) {
    m1 = fmaxf(m1, srow[w][0][j]);
    m2 = fmaxf(m2, srow[w][1][j]);
  }
  #pragma unroll
  for (int s = 32; s > 0; s >>= 1) {
    m1 = fmaxf(m1, __shfl_xor(m1, s));
    m2 = fmaxf(m2, __shfl_xor(m2, s));
  }
  float l1 = 0.f, l2 = 0.f;
  for (int j = lane; j <= t; j += 64) {
    float e1 = expf(srow[w][0][j] - m1);
    float e2 = expf(srow[w][1][j] - m2);
    srow[w][0][j] = e1;
    srow[w][1][j] = e2;
    l1 += e1; l2 += e2;
  }
  #pragma unroll
  for (int s = 32; s > 0; s >>= 1) { l1 += __shfl_xor(l1, s); l2 += __shfl_xor(l2, s); }
  for (int j = lane; j <= t; j += 64) {
    srow[w][0][j] = srow[w][0][j] / l1;         // per-element normalize like ref
    srow[w][1][j] = srow[w][1][j] / l2;
  }

  // ---- PV: serial over j, coalesced V reads across lanes ----
  float o1 = 0.f, o2 = 0.f;
  const float* vbase = vv + tokbase * 1024 + h * 64 + lane;
  for (int j = 0; j <= t; ++j) {
    float vval = vbase[(size_t)j * 1024];
    o1 = __builtin_fmaf(srow[w][0][j], vval, o1);
    o2 = __builtin_fmaf(srow[w][1][j], vval, o2);
  }
  float t2 = lam * o2;
  float oo = o1 - t2;
  out[(tokbase + t) * 1024 + h * 64 + lane] = oo;
}

// ===== router: f32 fmaf logits, softmax over 8, first-max argmax =====
__global__ __launch_bounds__(256) void k_router(const float* __restrict__ hm,
                                                const float* __restrict__ rw,
                                                int* __restrict__ idx,
                                                float* __restrict__ topp)
{
  #pragma clang fp contract(off)
  int tid = threadIdx.x;
  int tg = tid >> 3, e = tid & 7;
  int m = blockIdx.x * 32 + tg;
  const float* hr = hm + (size_t)m * 1024;
  const float* wr = rw + (size_t)e * 1024;
  float l = 0.f;
  for (int dd = 0; dd < 1024; ++dd) l = __builtin_fmaf(hr[dd], wr[dd], l);
  float mx = l;
  #pragma unroll
  for (int off = 1; off < 8; off <<= 1) mx = fmaxf(mx, __shfl_xor(mx, off, 8));
  float p = expf(l - mx);
  float den = p;
  #pragma unroll
  for (int off = 1; off < 8; off <<= 1) den += __shfl_xor(den, off, 8);
  float prob = p / den;
  float pm = prob;
  #pragma unroll
  for (int off = 1; off < 8; off <<= 1) pm = fmaxf(pm, __shfl_xor(pm, off, 8));
  unsigned long long ball = __ballot(prob == pm);
  int grp = (tid & 63) >> 3;
  int first = __ffsll((unsigned long long)((ball >> (grp * 8)) & 0xFFull)) - 1;
  if (e == 0) { idx[m] = first; topp[m] = pm; }
}

// ===== final: x1 + (shared + routed) =====
__global__ __launch_bounds__(256) void k_final(const float* __restrict__ x1,
                                               const float* __restrict__ so,
                                               const float* __restrict__ rt,
                                               float* __restrict__ out) {
  #pragma clang fp contract(off)
  int i = blockIdx.x * 256 + threadIdx.x;
  float moe = so[i] + rt[i];
  out[i] = x1[i] + moe;
}

extern "C" void kernel_launch(void* const* d_in, const int* in_sizes, int n_in,
                              void* d_out, int out_size, void* d_ws, size_t ws_size,
                              hipStream_t stream) {
  const float* x   = (const float*)d_in[0];
  const float* Wq  = (const float*)d_in[2];
  const float* Wk  = (const float*)d_in[3];
  const float* Wv  = (const float*)d_in[4];
  const float* Wo  = (const float*)d_in[5];
  const float* lq  = (const float*)d_in[6];
  const float* lk  = (const float*)d_in[7];
  const float* qng = (const float*)d_in[8];
  const float* qnb = (const float*)d_in[9];
  const float* kng = (const float*)d_in[10];
  const float* knb = (const float*)d_in[11];
  const float* ag  = (const float*)d_in[12];
  const float* ab  = (const float*)d_in[13];
  const float* fg  = (const float*)d_in[14];
  const float* fb  = (const float*)d_in[15];
  const float* mg  = (const float*)d_in[16];
  const float* mb  = (const float*)d_in[17];
  const float* sw1 = (const float*)d_in[18];
  const float* sw2 = (const float*)d_in[19];
  const float* ew1 = (const float*)d_in[20];
  const float* ew2 = (const float*)d_in[21];
  const float* rw  = (const float*)d_in[22];

  float* ws = (float*)d_ws;
  size_t o = 0;
  float* scWq = ws + o; o += 2048;
  float* scWk = ws + o; o += 2048;
  float* scWv = ws + o; o += 1024;
  float* scWo = ws + o; o += 1024;
  float* scS1 = ws + o; o += 2048;
  float* scS2 = ws + o; o += 1024;
  float* scE1 = ws + o; o += 8 * 2048;
  float* scE2 = ws + o; o += 8 * 1024;
  float* lam  = ws + o; o += 16;
  float* TOPP = ws + o; o += 2048;
  int*   IDX  = (int*)(ws + o); o += 2048;
  o = (o + 63) & ~(size_t)63;

  const size_t MQ = (size_t)M_ * 2048;
  const size_t MD = (size_t)M_ * 1024;
  float* R1 = ws + o;                 // QP -> (X1 | HM)
  float* R2 = ws + o + MQ;            // KP -> SM -> T1
  float* R3 = ws + o + 2 * MQ;        // VV -> SO
  float* R4 = ws + o + 2 * MQ + MD;   // H1 -> AO -> RT

  float* QP = R1;  float* X1 = R1;  float* HM = R1 + MD;
  float* KP = R2;  float* SM = R2;  float* T1 = R2;
  float* VV = R3;  float* SO = R3;
  float* H1 = R4;  float* AO = R4;  float* RT = R4;

  // scales + lambda
  k_scale<<<2048,     64, 0, stream>>>(Wq,  1024, scWq);
  k_scale<<<2048,     64, 0, stream>>>(Wk,  1024, scWk);
  k_scale<<<1024,     64, 0, stream>>>(Wv,  1024, scWv);
  k_scale<<<1024,     64, 0, stream>>>(Wo,  1024, scWo);
  k_scale<<<2048,     64, 0, stream>>>(sw1, 1024, scS1);
  k_scale<<<1024,     64, 0, stream>>>(sw2, 2048, scS2);
  k_scale<<<8 * 2048, 64, 0, stream>>>(ew1, 1024, scE1);
  k_scale<<<8 * 1024, 64, 0, stream>>>(ew2, 2048, scE2);
  k_lambda<<<1, 64, 0, stream>>>(lq, lk, lam);

  // attention block
  k_layernorm<<<M_, 256, 0, stream>>>(x, ag, ab, H1, 1024);
  k_gemm<0><<<dim3(16,16), 256, 0, stream>>>(H1, 1024, Wq, scWq, QP, 2048, 1024, nullptr, nullptr, nullptr, 0);
  k_gemm<0><<<dim3(16,16), 256, 0, stream>>>(H1, 1024, Wk, scWk, KP, 2048, 1024, nullptr, nullptr, nullptr, 0);
  k_gemm<0><<<dim3(8,16),  256, 0, stream>>>(H1, 1024, Wv, scWv, VV, 1024, 1024, nullptr, nullptr, nullptr, 0);
  k_layernorm<<<M_, 256, 0, stream>>>(QP, qng, qnb, QP, 2048);
  k_layernorm<<<M_, 256, 0, stream>>>(KP, kng, knb, KP, 2048);
  k_attn2<<<dim3(32, 256), 256, 0, stream>>>(QP, KP, VV, lam, AO);   // AO over H1 (dead)
  k_gemm<2><<<dim3(8,16), 256, 0, stream>>>(AO, 1024, Wo, scWo, X1, 1024, 1024, x, nullptr, nullptr, 0);

  // MoE block
  k_layernorm<<<M_, 256, 0, stream>>>(X1, fg, fb, HM, 1024);
  k_layernorm<<<M_, 256, 0, stream>>>(HM, mg, mb, HM, 1024);
  k_router<<<M_ / 32, 256, 0, stream>>>(HM, rw, IDX, TOPP);

  // shared path
  k_gemm<1><<<dim3(16,16), 256, 0, stream>>>(HM, 1024, sw1, scS1, SM, 2048, 1024, nullptr, nullptr, nullptr, 0);
  k_gemm<0><<<dim3(8,16),  256, 0, stream>>>(SM, 2048, sw2, scS2, SO, 1024, 2048, nullptr, nullptr, nullptr, 0);

  // routed experts: dense per expert, conditional epilogue (e=0 zeroes rest)
  for (int e = 0; e < E_; ++e) {
    k_gemm<1><<<dim3(16,16), 256, 0, stream>>>(HM, 1024, ew1 + (size_t)e * F_ * D_, scE1 + (size_t)e * F_,
                                               T1, 2048, 1024, nullptr, nullptr, nullptr, 0);
    k_gemm<4><<<dim3(8,16),  256, 0, stream>>>(T1, 2048, ew2 + (size_t)e * D_ * F_, scE2 + (size_t)e * D_,
                                               RT, 1024, 2048, nullptr, IDX, TOPP, e);
  }

  k_final<<<8192, 256, 0, stream>>>(X1, SO, RT, (float*)d_out);
}

// Round 7
// 3044.139 us; speedup vs baseline: 2.2522x; 2.2522x over previous
//
#include <hip/hip_runtime.h>
#include <hip/hip_bf16.h>

#define B_ 2
#define T_ 1024
#define D_ 1024
#define H_ 16
#define DH_ 64
#define F_ 2048
#define E_ 8
#define M_ 2048   // B*T tokens

// ===== numpy-style pairwise sum of a[0..K), K in {1024, 2048}, one wave =====
template<bool ABS>
__device__ __forceinline__ float np_pairwise_wave(const float* a, int K, int lane) {
  int nb = K >> 7;
  float s = 0.f;
  if (lane < nb) {
    const float* p = a + (lane << 7);
    float r[8];
    #pragma unroll
    for (int j = 0; j < 8; ++j) r[j] = ABS ? fabsf(p[j]) : p[j];
    for (int i = 8; i < 128; i += 8)
      #pragma unroll
      for (int j = 0; j < 8; ++j) r[j] += ABS ? fabsf(p[i + j]) : p[i + j];
    s = ((r[0] + r[1]) + (r[2] + r[3])) + ((r[4] + r[5]) + (r[6] + r[7]));
  }
  for (int off = 1; off < nb; off <<= 1) s += __shfl_xor(s, off);
  return __shfl(s, 0);
}

// ===== row scale: f32 mean(|W|) pairwise, clipped at 1e-5 =====
__global__ __launch_bounds__(64) void k_scale(const float* __restrict__ W, int K,
                                              float* __restrict__ out) {
  int r = blockIdx.x, lane = threadIdx.x;
  float S = np_pairwise_wave<true>(W + (size_t)r * K, K, lane);
  if (lane == 0) {
    float m = S / (float)K;
    out[r] = fmaxf(m, 1e-5f);
  }
}

// ===== lambda = clip(expf(mean(lq)-mean(lk)), 0.1, 2.0) =====
__global__ __launch_bounds__(64) void k_lambda(const float* __restrict__ lq,
                                               const float* __restrict__ lk,
                                               float* __restrict__ lam) {
  int lane = threadIdx.x;
  float mq = np_pairwise_wave<false>(lq, 1024, lane) / 1024.0f;
  float mk = np_pairwise_wave<false>(lk, 1024, lane) / 1024.0f;
  if (lane == 0) {
    float l = expf(mq - mk);
    lam[0] = fminf(2.0f, fmaxf(0.1f, l));
  }
}

// ===== layernorm, f32 pairwise stats, in==out allowed =====
__global__ __launch_bounds__(256) void k_layernorm(const float* __restrict__ in,
                                                   const float* __restrict__ g,
                                                   const float* __restrict__ b,
                                                   float* __restrict__ out, int Dd) {
  #pragma clang fp contract(off)
  __shared__ float row[2048];
  __shared__ float sq[2048];
  __shared__ float stat[2];
  int m = blockIdx.x, tid = threadIdx.x;
  const float* src = in + (size_t)m * Dd;
  for (int d = tid; d < Dd; d += 256) row[d] = src[d];
  __syncthreads();
  if (tid < 64) {
    float S = np_pairwise_wave<false>(row, Dd, tid);
    if (tid == 0) stat[0] = S;
  }
  __syncthreads();
  float mean = stat[0] / (float)Dd;
  for (int d = tid; d < Dd; d += 256) { float t = row[d] - mean; sq[d] = t * t; }
  __syncthreads();
  if (tid < 64) {
    float S = np_pairwise_wave<false>(sq, Dd, tid);
    if (tid == 0) stat[1] = S;
  }
  __syncthreads();
  float var = stat[1] / (float)Dd;
  float rs = 1.0f / sqrtf(var + 1e-5f);
  float* dst = out + (size_t)m * Dd;
  for (int d = tid; d < Dd; d += 256) {
    float t = row[d] - mean;
    float u = t * rs;
    float v = u * g[d];
    dst[d] = v + b[d];
  }
}

// ===== f32 GEMM, fmaf chain, faithful f32 straight-through quant =====
// EPI: 0 store, 1 silu, 2 add residual (dense), 3 scatter+topp (XM=2)
// XM : 0 dense M=2048; 1 expert gather-in/compact-out; 2 compact-in/scatter-out
template<int EPI, int XM>
__global__ __launch_bounds__(256) void k_gemm(const float* __restrict__ A, int lda,
    const float* __restrict__ Wt, const float* __restrict__ scf,
    float* __restrict__ Cout, int ldc, int N, int K,
    const float* __restrict__ res,
    const int* __restrict__ offs, const int* __restrict__ tlist,
    const float* __restrict__ topp)
{
  #pragma clang fp contract(off)
  int e = XM ? blockIdx.z : 0;
  int mbase = 0, mcount = M_;
  const float* W = Wt;
  const float* sc = scf;
  if (XM) {
    mbase = offs[e]; mcount = offs[e + 1] - mbase;
    W  = Wt  + (size_t)e * N * K;
    sc = scf + (size_t)e * N;
  }
  int m0 = blockIdx.y * 128;
  if (m0 >= mcount) return;
  int n0 = blockIdx.x * 128;

  __shared__ float As[16][128];
  __shared__ float Bs[16][128];
  int tid = threadIdx.x;
  int tx = tid & 15, ty = tid >> 4;
  int lm = tid >> 1;
  int lc = (tid & 1) * 8;

  int am  = m0 + lm;
  int amc = (am < mcount) ? am : (mcount - 1);
  int arow;
  if (XM == 1)      arow = tlist[mbase + amc];
  else if (XM == 2) arow = mbase + amc;
  else              arow = am;
  const float* Arow = A + (size_t)arow * lda;
  const float* Wrow = W + (size_t)(n0 + lm) * K;
  float wscale = sc[n0 + lm];

  float acc[8][8];
  #pragma unroll
  for (int j = 0; j < 8; j++)
    #pragma unroll
    for (int i = 0; i < 8; i++) acc[j][i] = 0.f;

  for (int kt = 0; kt < K; kt += 16) {
    float4 a0 = *reinterpret_cast<const float4*>(Arow + kt + lc);
    float4 a1 = *reinterpret_cast<const float4*>(Arow + kt + lc + 4);
    As[lc + 0][lm] = a0.x; As[lc + 1][lm] = a0.y; As[lc + 2][lm] = a0.z; As[lc + 3][lm] = a0.w;
    As[lc + 4][lm] = a1.x; As[lc + 5][lm] = a1.y; As[lc + 6][lm] = a1.z; As[lc + 7][lm] = a1.w;
    float4 w0 = *reinterpret_cast<const float4*>(Wrow + kt + lc);
    float4 w1 = *reinterpret_cast<const float4*>(Wrow + kt + lc + 4);
    float wv[8] = {w0.x, w0.y, w0.z, w0.w, w1.x, w1.y, w1.z, w1.w};
    #pragma unroll
    for (int j = 0; j < 8; j++) {
      float qq = rintf(wv[j] / wscale);
      qq = fminf(1.f, fmaxf(-1.f, qq));
      float aq = qq * wscale;
      float t  = aq - wv[j];
      Bs[lc + j][lm] = wv[j] + t;     // faithful straight-through f32
    }
    __syncthreads();
    #pragma unroll
    for (int k = 0; k < 16; k++) {
      float a[8], w[8];
      #pragma unroll
      for (int j = 0; j < 8; j++) a[j] = As[k][ty * 8 + j];
      #pragma unroll
      for (int i = 0; i < 8; i++) w[i] = Bs[k][tx * 8 + i];
      #pragma unroll
      for (int j = 0; j < 8; j++)
        #pragma unroll
        for (int i = 0; i < 8; i++) acc[j][i] = __builtin_fmaf(a[j], w[i], acc[j][i]);
    }
    __syncthreads();
  }

  #pragma unroll
  for (int j = 0; j < 8; j++) {
    int mrow = m0 + ty * 8 + j;
    if (XM && mrow >= mcount) continue;
    int orow;
    if (XM == 1)      orow = mbase + mrow;          // compact out
    else if (XM == 2) orow = tlist[mbase + mrow];   // scatter out
    else              orow = mrow;
    float* crow = Cout + (size_t)orow * ldc + n0;
    if (EPI == 3) {
      float tp = topp[orow];
      #pragma unroll
      for (int i = 0; i < 8; i++) crow[tx * 8 + i] = acc[j][i] * tp;
    } else if (EPI == 2) {
      const float* rrow = res + (size_t)orow * ldc + n0;
      #pragma unroll
      for (int i = 0; i < 8; i++) crow[tx * 8 + i] = rrow[tx * 8 + i] + acc[j][i];
    } else {
      #pragma unroll
      for (int i = 0; i < 8; i++) {
        float v = acc[j][i];
        if (EPI == 1) v = v * (1.0f / (1.0f + expf(-v)));
        crow[tx * 8 + i] = v;
      }
    }
  }
}

// ===== differential attention v3: LDS K-tiles (coalesced), no shuffles, ILP =====
// Block = (b,h) x 4 rows t0..t0+3 (warp w owns row t0+w). All barriers
// block-uniform; score compute unconditional per lane (write-guarded only).
__global__ __launch_bounds__(256) void k_attn3(const float* __restrict__ q,
                                               const float* __restrict__ kk,
                                               const float* __restrict__ vv,
                                               const float* __restrict__ lamp,
                                               float* __restrict__ out)
{
  #pragma clang fp contract(off)
  __shared__ float ktile[64][65];
  __shared__ float srow[4][2][1024];
  __shared__ float qs[4][2][64];
  int bh = blockIdx.x;            // 0..31
  int b = bh >> 4, h = bh & 15;
  int w = threadIdx.x >> 6, lane = threadIdx.x & 63;
  int t0 = blockIdx.y * 4;
  int t = t0 + w;
  size_t tokbase = (size_t)b * T_;
  float lam = lamp[0];

  const float* qrow = q + (tokbase + t) * 2048 + h * 64;
  qs[w][0][lane] = qrow[lane];          // warp-private LDS, wave-sync suffices
  qs[w][1][lane] = qrow[1024 + lane];

  int jtmax = t0 >> 6;    // t0..t0+3 in same 64-tile since t0 % 4 == 0

  // ---- scores: tile over j, stage K in LDS coalesced, 4-chain fmaf ----
  for (int jt = 0; jt <= jtmax; ++jt) {
    int j0 = jt << 6;
    for (int g = 0; g < 2; ++g) {
      __syncthreads();
      const float* kb = kk + (tokbase + j0) * 2048 + g * 1024 + h * 64;
      #pragma unroll
      for (int it = 0; it < 16; ++it) {
        int jr = it * 4 + w;
        ktile[lane][jr] = kb[(size_t)jr * 2048 + lane];   // coalesced read
      }
      __syncthreads();
      // all lanes compute (tile fully valid); guard only the write
      float sa = 0.f, sb = 0.f, sc_ = 0.f, sd = 0.f;
      const float* qg = qs[w][g];
      #pragma unroll
      for (int dd = 0; dd < 64; dd += 4) {
        sa = __builtin_fmaf(qg[dd + 0], ktile[dd + 0][lane], sa);
        sb = __builtin_fmaf(qg[dd + 1], ktile[dd + 1][lane], sb);
        sc_ = __builtin_fmaf(qg[dd + 2], ktile[dd + 2][lane], sc_);
        sd = __builtin_fmaf(qg[dd + 3], ktile[dd + 3][lane], sd);
      }
      float s = (sa + sb) + (sc_ + sd);
      int j = j0 + lane;
      if (j <= t) srow[w][g][j] = s * 0.125f;
    }
  }

  // ---- dual softmax over j <= t (warp-private, like k_attn2) ----
  float m1 = -1e30f, m2 = -1e30f;
  for (int j = lane; j <= t; j += 64) {
    m1 = fmaxf(m1, srow[w][0][j]);
    m2 = fmaxf(m2, srow[w][1][j]);
  }
  #pragma unroll
  for (int s = 32; s > 0; s >>= 1) {
    m1 = fmaxf(m1, __shfl_xor(m1, s));
    m2 = fmaxf(m2, __shfl_xor(m2, s));
  }
  float l1 = 0.f, l2 = 0.f;
  for (int j = lane; j <= t; j += 64) {
    float e1 = expf(srow[w][0][j] - m1);
    float e2 = expf(srow[w][1][j] - m2);
    srow[w][0][j] = e1;
    srow[w][1][j] = e2;
    l1 += e1; l2 += e2;
  }
  #pragma unroll
  for (int s = 32; s > 0; s >>= 1) { l1 += __shfl_xor(l1, s); l2 += __shfl_xor(l2, s); }
  for (int j = lane; j <= t; j += 64) {
    srow[w][0][j] = srow[w][0][j] / l1;
    srow[w][1][j] = srow[w][1][j] / l2;
  }

  // ---- PV: direct coalesced V reads, 4 independent chains each ----
  float o1a = 0.f, o1b = 0.f, o1c = 0.f, o1d = 0.f;
  float o2a = 0.f, o2b = 0.f, o2c = 0.f, o2d = 0.f;
  const float* vb = vv + tokbase * 1024 + h * 64 + lane;
  const float* p0 = srow[w][0];
  const float* p1 = srow[w][1];
  int j = 0;
  for (; j + 3 <= t; j += 4) {
    float v0 = vb[(size_t)(j + 0) * 1024];
    float v1 = vb[(size_t)(j + 1) * 1024];
    float v2 = vb[(size_t)(j + 2) * 1024];
    float v3 = vb[(size_t)(j + 3) * 1024];
    o1a = __builtin_fmaf(p0[j + 0], v0, o1a);
    o1b = __builtin_fmaf(p0[j + 1], v1, o1b);
    o1c = __builtin_fmaf(p0[j + 2], v2, o1c);
    o1d = __builtin_fmaf(p0[j + 3], v3, o1d);
    o2a = __builtin_fmaf(p1[j + 0], v0, o2a);
    o2b = __builtin_fmaf(p1[j + 1], v1, o2b);
    o2c = __builtin_fmaf(p1[j + 2], v2, o2c);
    o2d = __builtin_fmaf(p1[j + 3], v3, o2d);
  }
  for (; j <= t; ++j) {
    float v0 = vb[(size_t)j * 1024];
    o1a = __builtin_fmaf(p0[j], v0, o1a);
    o2a = __builtin_fmaf(p1[j], v0, o2a);
  }
  float o1 = (o1a + o1b) + (o1c + o1d);
  float o2 = (o2a + o2b) + (o2c + o2d);
  float t2 = lam * o2;
  float oo = o1 - t2;
  out[(tokbase + t) * 1024 + h * 64 + lane] = oo;
}

// ===== router: f32 fmaf logits, softmax over 8, first-max argmax =====
__global__ __launch_bounds__(256) void k_router(const float* __restrict__ hm,
                                                const float* __restrict__ rw,
                                                int* __restrict__ idx,
                                                float* __restrict__ topp)
{
  #pragma clang fp contract(off)
  int tid = threadIdx.x;
  int tg = tid >> 3, e = tid & 7;
  int m = blockIdx.x * 32 + tg;
  const float* hr = hm + (size_t)m * 1024;
  const float* wr = rw + (size_t)e * 1024;
  float l = 0.f;
  for (int dd = 0; dd < 1024; ++dd) l = __builtin_fmaf(hr[dd], wr[dd], l);
  float mx = l;
  #pragma unroll
  for (int off = 1; off < 8; off <<= 1) mx = fmaxf(mx, __shfl_xor(mx, off, 8));
  float p = expf(l - mx);
  float den = p;
  #pragma unroll
  for (int off = 1; off < 8; off <<= 1) den += __shfl_xor(den, off, 8);
  float prob = p / den;
  float pm = prob;
  #pragma unroll
  for (int off = 1; off < 8; off <<= 1) pm = fmaxf(pm, __shfl_xor(pm, off, 8));
  unsigned long long ball = __ballot(prob == pm);
  int grp = (tid & 63) >> 3;
  int first = __ffsll((unsigned long long)((ball >> (grp * 8)) & 0xFFull)) - 1;
  if (e == 0) { idx[m] = first; topp[m] = pm; }
}

// ===== deterministic token compaction: counts + offsets + ordered fill =====
// One block, 512 threads = 8 waves; wave e handles expert e. tlist is
// token-ascending within each expert (ballot prefix) -> fully deterministic.
__global__ __launch_bounds__(512) void k_route_fill(const int* __restrict__ idx,
                                                    int* __restrict__ offs,
                                                    int* __restrict__ tlist)
{
  __shared__ int cnt[8];
  __shared__ int off[9];
  int w = threadIdx.x >> 6, lane = threadIdx.x & 63;
  int total = 0;
  for (int it = 0; it < M_ / 64; ++it) {
    int tok = it * 64 + lane;
    unsigned long long m = __ballot(idx[tok] == w);
    total += __popcll(m);
  }
  if (lane == 0) cnt[w] = total;
  __syncthreads();
  if (threadIdx.x == 0) {
    int o = 0;
    for (int e = 0; e < 8; ++e) { off[e] = o; o += cnt[e]; }
    off[8] = o;
    for (int e = 0; e < 9; ++e) offs[e] = off[e];
  }
  __syncthreads();
  int base = off[w];
  for (int it = 0; it < M_ / 64; ++it) {
    int tok = it * 64 + lane;
    bool sel = (idx[tok] == w);
    unsigned long long m = __ballot(sel);
    if (sel) {
      int pos = base + __popcll(m & ((1ull << lane) - 1ull));
      tlist[pos] = tok;
    }
    base += __popcll(m);
  }
}

// ===== final: x1 + (shared + routed) =====
__global__ __launch_bounds__(256) void k_final(const float* __restrict__ x1,
                                               const float* __restrict__ so,
                                               const float* __restrict__ rt,
                                               float* __restrict__ out) {
  #pragma clang fp contract(off)
  int i = blockIdx.x * 256 + threadIdx.x;
  float moe = so[i] + rt[i];
  out[i] = x1[i] + moe;
}

extern "C" void kernel_launch(void* const* d_in, const int* in_sizes, int n_in,
                              void* d_out, int out_size, void* d_ws, size_t ws_size,
                              hipStream_t stream) {
  const float* x   = (const float*)d_in[0];
  const float* Wq  = (const float*)d_in[2];
  const float* Wk  = (const float*)d_in[3];
  const float* Wv  = (const float*)d_in[4];
  const float* Wo  = (const float*)d_in[5];
  const float* lq  = (const float*)d_in[6];
  const float* lk  = (const float*)d_in[7];
  const float* qng = (const float*)d_in[8];
  const float* qnb = (const float*)d_in[9];
  const float* kng = (const float*)d_in[10];
  const float* knb = (const float*)d_in[11];
  const float* ag  = (const float*)d_in[12];
  const float* ab  = (const float*)d_in[13];
  const float* fg  = (const float*)d_in[14];
  const float* fb  = (const float*)d_in[15];
  const float* mg  = (const float*)d_in[16];
  const float* mb  = (const float*)d_in[17];
  const float* sw1 = (const float*)d_in[18];
  const float* sw2 = (const float*)d_in[19];
  const float* ew1 = (const float*)d_in[20];
  const float* ew2 = (const float*)d_in[21];
  const float* rw  = (const float*)d_in[22];

  float* ws = (float*)d_ws;
  size_t o = 0;
  float* scWq = ws + o; o += 2048;
  float* scWk = ws + o; o += 2048;
  float* scWv = ws + o; o += 1024;
  float* scWo = ws + o; o += 1024;
  float* scS1 = ws + o; o += 2048;
  float* scS2 = ws + o; o += 1024;
  float* scE1 = ws + o; o += 8 * 2048;
  float* scE2 = ws + o; o += 8 * 1024;
  float* lam  = ws + o; o += 16;
  float* TOPP = ws + o; o += 2048;
  int*   IDX  = (int*)(ws + o); o += 2048;
  int*   OFFS = (int*)(ws + o); o += 16;
  int*   TLIST= (int*)(ws + o); o += 2048;
  o = (o + 63) & ~(size_t)63;

  const size_t MQ = (size_t)M_ * 2048;
  const size_t MD = (size_t)M_ * 1024;
  float* R1 = ws + o;                 // QP -> (X1 | HM)
  float* R2 = ws + o + MQ;            // KP -> SM -> T1(compact)
  float* R3 = ws + o + 2 * MQ;        // VV -> SO
  float* R4 = ws + o + 2 * MQ + MD;   // H1 -> AO -> RT

  float* QP = R1;  float* X1 = R1;  float* HM = R1 + MD;
  float* KP = R2;  float* SM = R2;  float* T1 = R2;
  float* VV = R3;  float* SO = R3;
  float* H1 = R4;  float* AO = R4;  float* RT = R4;

  // scales + lambda
  k_scale<<<2048,     64, 0, stream>>>(Wq,  1024, scWq);
  k_scale<<<2048,     64, 0, stream>>>(Wk,  1024, scWk);
  k_scale<<<1024,     64, 0, stream>>>(Wv,  1024, scWv);
  k_scale<<<1024,     64, 0, stream>>>(Wo,  1024, scWo);
  k_scale<<<2048,     64, 0, stream>>>(sw1, 1024, scS1);
  k_scale<<<1024,     64, 0, stream>>>(sw2, 2048, scS2);
  k_scale<<<8 * 2048, 64, 0, stream>>>(ew1, 1024, scE1);
  k_scale<<<8 * 1024, 64, 0, stream>>>(ew2, 2048, scE2);
  k_lambda<<<1, 64, 0, stream>>>(lq, lk, lam);

  // attention block (router-relevant numerics identical to round 6 GEMMs)
  k_layernorm<<<M_, 256, 0, stream>>>(x, ag, ab, H1, 1024);
  k_gemm<0,0><<<dim3(16,16), 256, 0, stream>>>(H1, 1024, Wq, scWq, QP, 2048, 2048, 1024, nullptr, nullptr, nullptr, nullptr);
  k_gemm<0,0><<<dim3(16,16), 256, 0, stream>>>(H1, 1024, Wk, scWk, KP, 2048, 2048, 1024, nullptr, nullptr, nullptr, nullptr);
  k_gemm<0,0><<<dim3(8,16),  256, 0, stream>>>(H1, 1024, Wv, scWv, VV, 1024, 1024, 1024, nullptr, nullptr, nullptr, nullptr);
  k_layernorm<<<M_, 256, 0, stream>>>(QP, qng, qnb, QP, 2048);
  k_layernorm<<<M_, 256, 0, stream>>>(KP, kng, knb, KP, 2048);
  k_attn3<<<dim3(32, 256), 256, 0, stream>>>(QP, KP, VV, lam, AO);   // AO over H1 (dead)
  k_gemm<2,0><<<dim3(8,16), 256, 0, stream>>>(AO, 1024, Wo, scWo, X1, 1024, 1024, 1024, x, nullptr, nullptr, nullptr);

  // MoE block
  k_layernorm<<<M_, 256, 0, stream>>>(X1, fg, fb, HM, 1024);
  k_layernorm<<<M_, 256, 0, stream>>>(HM, mg, mb, HM, 1024);
  k_router<<<M_ / 32, 256, 0, stream>>>(HM, rw, IDX, TOPP);
  k_route_fill<<<1, 512, 0, stream>>>(IDX, OFFS, TLIST);

  // shared path
  k_gemm<1,0><<<dim3(16,16), 256, 0, stream>>>(HM, 1024, sw1, scS1, SM, 2048, 2048, 1024, nullptr, nullptr, nullptr, nullptr);
  k_gemm<0,0><<<dim3(8,16),  256, 0, stream>>>(SM, 2048, sw2, scS2, SO, 1024, 1024, 2048, nullptr, nullptr, nullptr, nullptr);

  // routed experts: SPARSE top-1 (gather-in -> compact mid -> scatter-out)
  k_gemm<1,1><<<dim3(16,16,8), 256, 0, stream>>>(HM, 1024, ew1, scE1, T1, 2048, 2048, 1024, nullptr, OFFS, TLIST, nullptr);
  k_gemm<3,2><<<dim3(8,16,8),  256, 0, stream>>>(T1, 2048, ew2, scE2, RT, 1024, 1024, 2048, nullptr, OFFS, TLIST, TOPP);

  k_final<<<8192, 256, 0, stream>>>(X1, SO, RT, (float*)d_out);
}

// Round 8
// 1147.245 us; speedup vs baseline: 5.9760x; 2.6534x over previous
//
#include <hip/hip_runtime.h>
#include <hip/hip_bf16.h>

#define B_ 2
#define T_ 1024
#define D_ 1024
#define H_ 16
#define DH_ 64
#define F_ 2048
#define E_ 8
#define M_ 2048   // B*T tokens

typedef _Float16 half8 __attribute__((ext_vector_type(8)));
typedef float f32x4 __attribute__((ext_vector_type(4)));

// ===== numpy-style pairwise sum of a[0..K), K in {1024, 2048}, one wave =====
template<bool ABS>
__device__ __forceinline__ float np_pairwise_wave(const float* a, int K, int lane) {
  int nb = K >> 7;
  float s = 0.f;
  if (lane < nb) {
    const float* p = a + (lane << 7);
    float r[8];
    #pragma unroll
    for (int j = 0; j < 8; ++j) r[j] = ABS ? fabsf(p[j]) : p[j];
    for (int i = 8; i < 128; i += 8)
      #pragma unroll
      for (int j = 0; j < 8; ++j) r[j] += ABS ? fabsf(p[i + j]) : p[i + j];
    s = ((r[0] + r[1]) + (r[2] + r[3])) + ((r[4] + r[5]) + (r[6] + r[7]));
  }
  for (int off = 1; off < nb; off <<= 1) s += __shfl_xor(s, off);
  return __shfl(s, 0);
}

// ===== row scale: f32 mean(|W|) pairwise, clipped at 1e-5 =====
__global__ __launch_bounds__(64) void k_scale(const float* __restrict__ W, int K,
                                              float* __restrict__ out) {
  int r = blockIdx.x, lane = threadIdx.x;
  float S = np_pairwise_wave<true>(W + (size_t)r * K, K, lane);
  if (lane == 0) {
    float m = S / (float)K;
    out[r] = fmaxf(m, 1e-5f);
  }
}

// ===== lambda = clip(expf(mean(lq)-mean(lk)), 0.1, 2.0) =====
__global__ __launch_bounds__(64) void k_lambda(const float* __restrict__ lq,
                                               const float* __restrict__ lk,
                                               float* __restrict__ lam) {
  int lane = threadIdx.x;
  float mq = np_pairwise_wave<false>(lq, 1024, lane) / 1024.0f;
  float mk = np_pairwise_wave<false>(lk, 1024, lane) / 1024.0f;
  if (lane == 0) {
    float l = expf(mq - mk);
    lam[0] = fminf(2.0f, fmaxf(0.1f, l));
  }
}

// ===== layernorm, f32 pairwise stats, in==out allowed =====
__global__ __launch_bounds__(256) void k_layernorm(const float* __restrict__ in,
                                                   const float* __restrict__ g,
                                                   const float* __restrict__ b,
                                                   float* __restrict__ out, int Dd) {
  #pragma clang fp contract(off)
  __shared__ float row[2048];
  __shared__ float sq[2048];
  __shared__ float stat[2];
  int m = blockIdx.x, tid = threadIdx.x;
  const float* src = in + (size_t)m * Dd;
  for (int d = tid; d < Dd; d += 256) row[d] = src[d];
  __syncthreads();
  if (tid < 64) {
    float S = np_pairwise_wave<false>(row, Dd, tid);
    if (tid == 0) stat[0] = S;
  }
  __syncthreads();
  float mean = stat[0] / (float)Dd;
  for (int d = tid; d < Dd; d += 256) { float t = row[d] - mean; sq[d] = t * t; }
  __syncthreads();
  if (tid < 64) {
    float S = np_pairwise_wave<false>(sq, Dd, tid);
    if (tid == 0) stat[1] = S;
  }
  __syncthreads();
  float var = stat[1] / (float)Dd;
  float rs = 1.0f / sqrtf(var + 1e-5f);
  float* dst = out + (size_t)m * Dd;
  for (int d = tid; d < Dd; d += 256) {
    float t = row[d] - mean;
    float u = t * rs;
    float v = u * g[d];
    dst[d] = v + b[d];
  }
}

// ===== MFMA GEMM: C = scale_n * (A @ q[N,K]^T), fp16 hi/lo split (exact to ~1e-7 rel)
// a = hi + lo/2048 (both fp16, lo upscaled 2^11 to stay normal); q ternary fp16.
// Tile: block 128(M)x64(N), 4 waves (2Mx2N), wave 64x32 = 4x2 frags of 16x16x32.
// EPI: 0 store, 1 silu, 2 res+, 3 *topp scatter.  XM: 0 dense, 1 gather-in, 2 scatter-out.
template<int EPI, int XM>
__global__ __launch_bounds__(256) void k_mgemm(const float* __restrict__ A, int lda,
    const float* __restrict__ Wt, const float* __restrict__ scf,
    float* __restrict__ Cout, int ldc, int N, int K,
    const float* __restrict__ res,
    const int* __restrict__ offs, const int* __restrict__ tlist,
    const float* __restrict__ topp)
{
  int e = XM ? blockIdx.z : 0;
  int mbase = 0, mcount = M_;
  const float* W = Wt;
  const float* sc = scf;
  if (XM) {
    mbase = offs[e]; mcount = offs[e + 1] - mbase;
    W  = Wt  + (size_t)e * N * K;
    sc = scf + (size_t)e * N;
  }
  int m0 = blockIdx.y * 128;
  if (XM && m0 >= mcount) return;
  int n0 = blockIdx.x * 64;

  __shared__ __align__(16) _Float16 Ah[4][128][8];   // [k/8][row][k%8]
  __shared__ __align__(16) _Float16 Al[4][128][8];
  __shared__ __align__(16) _Float16 Qs[4][64][8];    // [k/8][col][k%8]

  int tid = threadIdx.x;
  // staging roles
  int lm  = tid >> 1;             // A row 0..127
  int kcA = (tid & 1) * 16;       // k base for A (16 floats)
  int lw  = tid >> 2;             // W row 0..63
  int kcW = (tid & 3) * 8;        // k base for W (8 floats)

  int am  = m0 + lm;
  int amc = XM ? ((am < mcount) ? am : (mcount - 1)) : am;
  int arow;
  if (XM == 1)      arow = tlist[mbase + amc];
  else if (XM == 2) arow = mbase + amc;
  else              arow = am;
  const float* Arow = A + (size_t)arow * lda;
  const float* Wrow = W + (size_t)(n0 + lw) * K;
  float wscale = sc[n0 + lw];

  // wave decomposition
  int wv = tid >> 6, lane = tid & 63;
  int wm = wv >> 1, wn = wv & 1;
  int ks = lane >> 4, fr = lane & 15;

  f32x4 acch[4][2], accl[4][2];
  #pragma unroll
  for (int i = 0; i < 4; i++)
    #pragma unroll
    for (int j = 0; j < 2; j++) { acch[i][j] = (f32x4)0.f; accl[i][j] = (f32x4)0.f; }

  for (int kt = 0; kt < K; kt += 32) {
    // ---- load + convert (regs) ----
    float4 a0 = *reinterpret_cast<const float4*>(Arow + kt + kcA);
    float4 a1 = *reinterpret_cast<const float4*>(Arow + kt + kcA + 4);
    float4 a2 = *reinterpret_cast<const float4*>(Arow + kt + kcA + 8);
    float4 a3 = *reinterpret_cast<const float4*>(Arow + kt + kcA + 12);
    float av[16] = {a0.x,a0.y,a0.z,a0.w, a1.x,a1.y,a1.z,a1.w,
                    a2.x,a2.y,a2.z,a2.w, a3.x,a3.y,a3.z,a3.w};
    half8 h0, h1, l0, l1;
    #pragma unroll
    for (int j = 0; j < 8; j++) {
      _Float16 h = (_Float16)av[j];
      h0[j] = h; l0[j] = (_Float16)((av[j] - (float)h) * 2048.0f);
      _Float16 g = (_Float16)av[8 + j];
      h1[j] = g; l1[j] = (_Float16)((av[8 + j] - (float)g) * 2048.0f);
    }
    float4 w0 = *reinterpret_cast<const float4*>(Wrow + kt + kcW);
    float4 w1 = *reinterpret_cast<const float4*>(Wrow + kt + kcW + 4);
    float wvv[8] = {w0.x,w0.y,w0.z,w0.w, w1.x,w1.y,w1.z,w1.w};
    half8 qh;
    #pragma unroll
    for (int j = 0; j < 8; j++) {
      float qq = rintf(wvv[j] / wscale);
      qq = fminf(1.f, fmaxf(-1.f, qq));
      qh[j] = (_Float16)qq;              // exact ternary
    }
    __syncthreads();   // previous iteration's reads done
    int sA = kcA >> 3;
    *reinterpret_cast<half8*>(&Ah[sA][lm][0])     = h0;
    *reinterpret_cast<half8*>(&Ah[sA + 1][lm][0]) = h1;
    *reinterpret_cast<half8*>(&Al[sA][lm][0])     = l0;
    *reinterpret_cast<half8*>(&Al[sA + 1][lm][0]) = l1;
    *reinterpret_cast<half8*>(&Qs[kcW >> 3][lw][0]) = qh;
    __syncthreads();
    // ---- fragments + MFMA ----
    half8 bfr0 = *reinterpret_cast<half8*>(&Qs[ks][wn * 32 + fr][0]);
    half8 bfr1 = *reinterpret_cast<half8*>(&Qs[ks][wn * 32 + 16 + fr][0]);
    #pragma unroll
    for (int i = 0; i < 4; i++) {
      half8 ah = *reinterpret_cast<half8*>(&Ah[ks][wm * 64 + i * 16 + fr][0]);
      half8 al = *reinterpret_cast<half8*>(&Al[ks][wm * 64 + i * 16 + fr][0]);
      acch[i][0] = __builtin_amdgcn_mfma_f32_16x16x32_f16(ah, bfr0, acch[i][0], 0, 0, 0);
      acch[i][1] = __builtin_amdgcn_mfma_f32_16x16x32_f16(ah, bfr1, acch[i][1], 0, 0, 0);
      accl[i][0] = __builtin_amdgcn_mfma_f32_16x16x32_f16(al, bfr0, accl[i][0], 0, 0, 0);
      accl[i][1] = __builtin_amdgcn_mfma_f32_16x16x32_f16(al, bfr1, accl[i][1], 0, 0, 0);
    }
  }

  // ---- epilogue: D col = lane&15, row = (lane>>4)*4 + r ----
  #pragma unroll
  for (int j = 0; j < 2; j++) {
    int col = n0 + wn * 32 + j * 16 + fr;
    float scl = sc[col];
    #pragma unroll
    for (int i = 0; i < 4; i++) {
      #pragma unroll
      for (int r = 0; r < 4; r++) {
        int lrow = m0 + wm * 64 + i * 16 + ks * 4 + r;   // row in (compact) M space
        if (XM && lrow >= mcount) continue;
        int orow;
        if (XM == 1)      orow = mbase + lrow;           // compact out
        else if (XM == 2) orow = tlist[mbase + lrow];    // scatter out
        else              orow = lrow;
        float v = (acch[i][j][r] + accl[i][j][r] * (1.0f / 2048.0f)) * scl;
        if (EPI == 1) v = v * (1.0f / (1.0f + expf(-v)));
        else if (EPI == 2) v = res[(size_t)orow * ldc + col] + v;
        else if (EPI == 3) v = v * topp[orow];
        Cout[(size_t)orow * ldc + col] = v;
      }
    }
  }
}

// ===== differential attention v3: LDS K-tiles (coalesced), no shuffles, ILP =====
__global__ __launch_bounds__(256) void k_attn3(const float* __restrict__ q,
                                               const float* __restrict__ kk,
                                               const float* __restrict__ vv,
                                               const float* __restrict__ lamp,
                                               float* __restrict__ out)
{
  #pragma clang fp contract(off)
  __shared__ float ktile[64][65];
  __shared__ float srow[4][2][1024];
  __shared__ float qs[4][2][64];
  int bh = blockIdx.x;            // 0..31
  int b = bh >> 4, h = bh & 15;
  int w = threadIdx.x >> 6, lane = threadIdx.x & 63;
  int t0 = blockIdx.y * 4;
  int t = t0 + w;
  size_t tokbase = (size_t)b * T_;
  float lam = lamp[0];

  const float* qrow = q + (tokbase + t) * 2048 + h * 64;
  qs[w][0][lane] = qrow[lane];
  qs[w][1][lane] = qrow[1024 + lane];

  int jtmax = t0 >> 6;

  for (int jt = 0; jt <= jtmax; ++jt) {
    int j0 = jt << 6;
    for (int g = 0; g < 2; ++g) {
      __syncthreads();
      const float* kb = kk + (tokbase + j0) * 2048 + g * 1024 + h * 64;
      #pragma unroll
      for (int it = 0; it < 16; ++it) {
        int jr = it * 4 + w;
        ktile[lane][jr] = kb[(size_t)jr * 2048 + lane];
      }
      __syncthreads();
      float sa = 0.f, sb = 0.f, sc_ = 0.f, sd = 0.f;
      const float* qg = qs[w][g];
      #pragma unroll
      for (int dd = 0; dd < 64; dd += 4) {
        sa = __builtin_fmaf(qg[dd + 0], ktile[dd + 0][lane], sa);
        sb = __builtin_fmaf(qg[dd + 1], ktile[dd + 1][lane], sb);
        sc_ = __builtin_fmaf(qg[dd + 2], ktile[dd + 2][lane], sc_);
        sd = __builtin_fmaf(qg[dd + 3], ktile[dd + 3][lane], sd);
      }
      float s = (sa + sb) + (sc_ + sd);
      int j = j0 + lane;
      if (j <= t) srow[w][g][j] = s * 0.125f;
    }
  }

  float m1 = -1e30f, m2 = -1e30f;
  for (int j = lane; j <= t; j += 64) {
    m1 = fmaxf(m1, srow[w][0][j]);
    m2 = fmaxf(m2, srow[w][1][j]);
  }
  #pragma unroll
  for (int s = 32; s > 0; s >>= 1) {
    m1 = fmaxf(m1, __shfl_xor(m1, s));
    m2 = fmaxf(m2, __shfl_xor(m2, s));
  }
  float l1 = 0.f, l2 = 0.f;
  for (int j = lane; j <= t; j += 64) {
    float e1 = expf(srow[w][0][j] - m1);
    float e2 = expf(srow[w][1][j] - m2);
    srow[w][0][j] = e1;
    srow[w][1][j] = e2;
    l1 += e1; l2 += e2;
  }
  #pragma unroll
  for (int s = 32; s > 0; s >>= 1) { l1 += __shfl_xor(l1, s); l2 += __shfl_xor(l2, s); }
  for (int j = lane; j <= t; j += 64) {
    srow[w][0][j] = srow[w][0][j] / l1;
    srow[w][1][j] = srow[w][1][j] / l2;
  }

  float o1a = 0.f, o1b = 0.f, o1c = 0.f, o1d = 0.f;
  float o2a = 0.f, o2b = 0.f, o2c = 0.f, o2d = 0.f;
  const float* vb = vv + tokbase * 1024 + h * 64 + lane;
  const float* p0 = srow[w][0];
  const float* p1 = srow[w][1];
  int j = 0;
  for (; j + 3 <= t; j += 4) {
    float v0 = vb[(size_t)(j + 0) * 1024];
    float v1 = vb[(size_t)(j + 1) * 1024];
    float v2 = vb[(size_t)(j + 2) * 1024];
    float v3 = vb[(size_t)(j + 3) * 1024];
    o1a = __builtin_fmaf(p0[j + 0], v0, o1a);
    o1b = __builtin_fmaf(p0[j + 1], v1, o1b);
    o1c = __builtin_fmaf(p0[j + 2], v2, o1c);
    o1d = __builtin_fmaf(p0[j + 3], v3, o1d);
    o2a = __builtin_fmaf(p1[j + 0], v0, o2a);
    o2b = __builtin_fmaf(p1[j + 1], v1, o2b);
    o2c = __builtin_fmaf(p1[j + 2], v2, o2c);
    o2d = __builtin_fmaf(p1[j + 3], v3, o2d);
  }
  for (; j <= t; ++j) {
    float v0 = vb[(size_t)j * 1024];
    o1a = __builtin_fmaf(p0[j], v0, o1a);
    o2a = __builtin_fmaf(p1[j], v0, o2a);
  }
  float o1 = (o1a + o1b) + (o1c + o1d);
  float o2 = (o2a + o2b) + (o2c + o2d);
  float t2 = lam * o2;
  float oo = o1 - t2;
  out[(tokbase + t) * 1024 + h * 64 + lane] = oo;
}

// ===== router: f32 fmaf logits, softmax over 8, first-max argmax =====
__global__ __launch_bounds__(256) void k_router(const float* __restrict__ hm,
                                                const float* __restrict__ rw,
                                                int* __restrict__ idx,
                                                float* __restrict__ topp)
{
  #pragma clang fp contract(off)
  int tid = threadIdx.x;
  int tg = tid >> 3, e = tid & 7;
  int m = blockIdx.x * 32 + tg;
  const float* hr = hm + (size_t)m * 1024;
  const float* wr = rw + (size_t)e * 1024;
  float l = 0.f;
  for (int dd = 0; dd < 1024; ++dd) l = __builtin_fmaf(hr[dd], wr[dd], l);
  float mx = l;
  #pragma unroll
  for (int off = 1; off < 8; off <<= 1) mx = fmaxf(mx, __shfl_xor(mx, off, 8));
  float p = expf(l - mx);
  float den = p;
  #pragma unroll
  for (int off = 1; off < 8; off <<= 1) den += __shfl_xor(den, off, 8);
  float prob = p / den;
  float pm = prob;
  #pragma unroll
  for (int off = 1; off < 8; off <<= 1) pm = fmaxf(pm, __shfl_xor(pm, off, 8));
  unsigned long long ball = __ballot(prob == pm);
  int grp = (tid & 63) >> 3;
  int first = __ffsll((unsigned long long)((ball >> (grp * 8)) & 0xFFull)) - 1;
  if (e == 0) { idx[m] = first; topp[m] = pm; }
}

// ===== deterministic token compaction (ballot prefix, token-ordered) =====
__global__ __launch_bounds__(512) void k_route_fill(const int* __restrict__ idx,
                                                    int* __restrict__ offs,
                                                    int* __restrict__ tlist)
{
  __shared__ int cnt[8];
  __shared__ int off[9];
  int w = threadIdx.x >> 6, lane = threadIdx.x & 63;
  int total = 0;
  for (int it = 0; it < M_ / 64; ++it) {
    int tok = it * 64 + lane;
    unsigned long long m = __ballot(idx[tok] == w);
    total += __popcll(m);
  }
  if (lane == 0) cnt[w] = total;
  __syncthreads();
  if (threadIdx.x == 0) {
    int o = 0;
    for (int e = 0; e < 8; ++e) { off[e] = o; o += cnt[e]; }
    off[8] = o;
    for (int e = 0; e < 9; ++e) offs[e] = off[e];
  }
  __syncthreads();
  int base = off[w];
  for (int it = 0; it < M_ / 64; ++it) {
    int tok = it * 64 + lane;
    bool sel = (idx[tok] == w);
    unsigned long long m = __ballot(sel);
    if (sel) {
      int pos = base + __popcll(m & ((1ull << lane) - 1ull));
      tlist[pos] = tok;
    }
    base += __popcll(m);
  }
}

// ===== final: x1 + (shared + routed) =====
__global__ __launch_bounds__(256) void k_final(const float* __restrict__ x1,
                                               const float* __restrict__ so,
                                               const float* __restrict__ rt,
                                               float* __restrict__ out) {
  #pragma clang fp contract(off)
  int i = blockIdx.x * 256 + threadIdx.x;
  float moe = so[i] + rt[i];
  out[i] = x1[i] + moe;
}

extern "C" void kernel_launch(void* const* d_in, const int* in_sizes, int n_in,
                              void* d_out, int out_size, void* d_ws, size_t ws_size,
                              hipStream_t stream) {
  const float* x   = (const float*)d_in[0];
  const float* Wq  = (const float*)d_in[2];
  const float* Wk  = (const float*)d_in[3];
  const float* Wv  = (const float*)d_in[4];
  const float* Wo  = (const float*)d_in[5];
  const float* lq  = (const float*)d_in[6];
  const float* lk  = (const float*)d_in[7];
  const float* qng = (const float*)d_in[8];
  const float* qnb = (const float*)d_in[9];
  const float* kng = (const float*)d_in[10];
  const float* knb = (const float*)d_in[11];
  const float* ag  = (const float*)d_in[12];
  const float* ab  = (const float*)d_in[13];
  const float* fg  = (const float*)d_in[14];
  const float* fb  = (const float*)d_in[15];
  const float* mg  = (const float*)d_in[16];
  const float* mb  = (const float*)d_in[17];
  const float* sw1 = (const float*)d_in[18];
  const float* sw2 = (const float*)d_in[19];
  const float* ew1 = (const float*)d_in[20];
  const float* ew2 = (const float*)d_in[21];
  const float* rw  = (const float*)d_in[22];

  float* ws = (float*)d_ws;
  size_t o = 0;
  float* scWq = ws + o; o += 2048;
  float* scWk = ws + o; o += 2048;
  float* scWv = ws + o; o += 1024;
  float* scWo = ws + o; o += 1024;
  float* scS1 = ws + o; o += 2048;
  float* scS2 = ws + o; o += 1024;
  float* scE1 = ws + o; o += 8 * 2048;
  float* scE2 = ws + o; o += 8 * 1024;
  float* lam  = ws + o; o += 16;
  float* TOPP = ws + o; o += 2048;
  int*   IDX  = (int*)(ws + o); o += 2048;
  int*   OFFS = (int*)(ws + o); o += 16;
  int*   TLIST= (int*)(ws + o); o += 2048;
  o = (o + 63) & ~(size_t)63;

  const size_t MQ = (size_t)M_ * 2048;
  const size_t MD = (size_t)M_ * 1024;
  float* R1 = ws + o;                 // QP -> (X1 | HM)
  float* R2 = ws + o + MQ;            // KP -> SM -> T1(compact)
  float* R3 = ws + o + 2 * MQ;        // VV -> SO
  float* R4 = ws + o + 2 * MQ + MD;   // H1 -> AO -> RT

  float* QP = R1;  float* X1 = R1;  float* HM = R1 + MD;
  float* KP = R2;  float* SM = R2;  float* T1 = R2;
  float* VV = R3;  float* SO = R3;
  float* H1 = R4;  float* AO = R4;  float* RT = R4;

  // scales + lambda
  k_scale<<<2048,     64, 0, stream>>>(Wq,  1024, scWq);
  k_scale<<<2048,     64, 0, stream>>>(Wk,  1024, scWk);
  k_scale<<<1024,     64, 0, stream>>>(Wv,  1024, scWv);
  k_scale<<<1024,     64, 0, stream>>>(Wo,  1024, scWo);
  k_scale<<<2048,     64, 0, stream>>>(sw1, 1024, scS1);
  k_scale<<<1024,     64, 0, stream>>>(sw2, 2048, scS2);
  k_scale<<<8 * 2048, 64, 0, stream>>>(ew1, 1024, scE1);
  k_scale<<<8 * 1024, 64, 0, stream>>>(ew2, 2048, scE2);
  k_lambda<<<1, 64, 0, stream>>>(lq, lk, lam);

  // attention block (MFMA fp16-split GEMMs: error ~1e-6, routing-safe)
  k_layernorm<<<M_, 256, 0, stream>>>(x, ag, ab, H1, 1024);
  k_mgemm<0,0><<<dim3(32,16), 256, 0, stream>>>(H1, 1024, Wq, scWq, QP, 2048, 2048, 1024, nullptr, nullptr, nullptr, nullptr);
  k_mgemm<0,0><<<dim3(32,16), 256, 0, stream>>>(H1, 1024, Wk, scWk, KP, 2048, 2048, 1024, nullptr, nullptr, nullptr, nullptr);
  k_mgemm<0,0><<<dim3(16,16), 256, 0, stream>>>(H1, 1024, Wv, scWv, VV, 1024, 1024, 1024, nullptr, nullptr, nullptr, nullptr);
  k_layernorm<<<M_, 256, 0, stream>>>(QP, qng, qnb, QP, 2048);
  k_layernorm<<<M_, 256, 0, stream>>>(KP, kng, knb, KP, 2048);
  k_attn3<<<dim3(32, 256), 256, 0, stream>>>(QP, KP, VV, lam, AO);   // AO over H1 (dead)
  k_mgemm<2,0><<<dim3(16,16), 256, 0, stream>>>(AO, 1024, Wo, scWo, X1, 1024, 1024, 1024, x, nullptr, nullptr, nullptr);

  // MoE block
  k_layernorm<<<M_, 256, 0, stream>>>(X1, fg, fb, HM, 1024);
  k_layernorm<<<M_, 256, 0, stream>>>(HM, mg, mb, HM, 1024);
  k_router<<<M_ / 32, 256, 0, stream>>>(HM, rw, IDX, TOPP);
  k_route_fill<<<1, 512, 0, stream>>>(IDX, OFFS, TLIST);

  // shared path
  k_mgemm<1,0><<<dim3(32,16), 256, 0, stream>>>(HM, 1024, sw1, scS1, SM, 2048, 2048, 1024, nullptr, nullptr, nullptr, nullptr);
  k_mgemm<0,0><<<dim3(16,16), 256, 0, stream>>>(SM, 2048, sw2, scS2, SO, 1024, 1024, 2048, nullptr, nullptr, nullptr, nullptr);

  // routed experts: SPARSE top-1 (gather-in -> compact mid -> scatter-out)
  k_mgemm<1,1><<<dim3(32,16,8), 256, 0, stream>>>(HM, 1024, ew1, scE1, T1, 2048, 2048, 1024, nullptr, OFFS, TLIST, nullptr);
  k_mgemm<3,2><<<dim3(16,16,8), 256, 0, stream>>>(T1, 2048, ew2, scE2, RT, 1024, 1024, 2048, nullptr, OFFS, TLIST, TOPP);

  k_final<<<8192, 256, 0, stream>>>(X1, SO, RT, (float*)d_out);
}

// Round 9
// 821.331 us; speedup vs baseline: 8.3474x; 1.3968x over previous
//
#include <hip/hip_runtime.h>
#include <hip/hip_bf16.h>

#define B_ 2
#define T_ 1024
#define D_ 1024
#define H_ 16
#define DH_ 64
#define F_ 2048
#define E_ 8
#define M_ 2048   // B*T tokens

typedef _Float16 half8 __attribute__((ext_vector_type(8)));
typedef float f32x4 __attribute__((ext_vector_type(4)));

// ===== numpy-style pairwise sum of a[0..K), K in {1024, 2048}, one wave =====
template<bool ABS>
__device__ __forceinline__ float np_pairwise_wave(const float* a, int K, int lane) {
  int nb = K >> 7;
  float s = 0.f;
  if (lane < nb) {
    const float* p = a + (lane << 7);
    float r[8];
    #pragma unroll
    for (int j = 0; j < 8; ++j) r[j] = ABS ? fabsf(p[j]) : p[j];
    for (int i = 8; i < 128; i += 8)
      #pragma unroll
      for (int j = 0; j < 8; ++j) r[j] += ABS ? fabsf(p[i + j]) : p[i + j];
    s = ((r[0] + r[1]) + (r[2] + r[3])) + ((r[4] + r[5]) + (r[6] + r[7]));
  }
  for (int off = 1; off < nb; off <<= 1) s += __shfl_xor(s, off);
  return __shfl(s, 0);
}

// ===== row scale: f32 mean(|W|) pairwise, clipped at 1e-5 =====
__global__ __launch_bounds__(64) void k_scale(const float* __restrict__ W, int K,
                                              float* __restrict__ out) {
  int r = blockIdx.x, lane = threadIdx.x;
  float S = np_pairwise_wave<true>(W + (size_t)r * K, K, lane);
  if (lane == 0) {
    float m = S / (float)K;
    out[r] = fmaxf(m, 1e-5f);
  }
}

// ===== lambda = clip(expf(mean(lq)-mean(lk)), 0.1, 2.0) =====
__global__ __launch_bounds__(64) void k_lambda(const float* __restrict__ lq,
                                               const float* __restrict__ lk,
                                               float* __restrict__ lam) {
  int lane = threadIdx.x;
  float mq = np_pairwise_wave<false>(lq, 1024, lane) / 1024.0f;
  float mk = np_pairwise_wave<false>(lk, 1024, lane) / 1024.0f;
  if (lane == 0) {
    float l = expf(mq - mk);
    lam[0] = fminf(2.0f, fmaxf(0.1f, l));
  }
}

// ===== layernorm, f32 pairwise stats, in==out allowed =====
__global__ __launch_bounds__(256) void k_layernorm(const float* __restrict__ in,
                                                   const float* __restrict__ g,
                                                   const float* __restrict__ b,
                                                   float* __restrict__ out, int Dd) {
  #pragma clang fp contract(off)
  __shared__ float row[2048];
  __shared__ float sq[2048];
  __shared__ float stat[2];
  int m = blockIdx.x, tid = threadIdx.x;
  const float* src = in + (size_t)m * Dd;
  for (int d = tid; d < Dd; d += 256) row[d] = src[d];
  __syncthreads();
  if (tid < 64) {
    float S = np_pairwise_wave<false>(row, Dd, tid);
    if (tid == 0) stat[0] = S;
  }
  __syncthreads();
  float mean = stat[0] / (float)Dd;
  for (int d = tid; d < Dd; d += 256) { float t = row[d] - mean; sq[d] = t * t; }
  __syncthreads();
  if (tid < 64) {
    float S = np_pairwise_wave<false>(sq, Dd, tid);
    if (tid == 0) stat[1] = S;
  }
  __syncthreads();
  float var = stat[1] / (float)Dd;
  float rs = 1.0f / sqrtf(var + 1e-5f);
  float* dst = out + (size_t)m * Dd;
  for (int d = tid; d < Dd; d += 256) {
    float t = row[d] - mean;
    float u = t * rs;
    float v = u * g[d];
    dst[d] = v + b[d];
  }
}

// ===== MFMA GEMM: C = scale_n * (A @ q[N,K]^T), fp16 hi/lo split =====
// EPI: 0 store, 1 silu, 2 res+, 3 *topp, 5 transposed store (for attention V)
// XM : 0 dense, 1 gather-in/compact-out, 2 compact-in/scatter-out
template<int EPI, int XM>
__global__ __launch_bounds__(256) void k_mgemm(const float* __restrict__ A, int lda,
    const float* __restrict__ Wt, const float* __restrict__ scf,
    float* __restrict__ Cout, int ldc, int N, int K,
    const float* __restrict__ res,
    const int* __restrict__ offs, const int* __restrict__ tlist,
    const float* __restrict__ topp)
{
  int e = XM ? blockIdx.z : 0;
  int mbase = 0, mcount = M_;
  const float* W = Wt;
  const float* sc = scf;
  if (XM) {
    mbase = offs[e]; mcount = offs[e + 1] - mbase;
    W  = Wt  + (size_t)e * N * K;
    sc = scf + (size_t)e * N;
  }
  int m0 = blockIdx.y * 128;
  if (XM && m0 >= mcount) return;
  int n0 = blockIdx.x * 64;

  __shared__ __align__(16) _Float16 Ah[4][128][8];   // [k/8][row][k%8]
  __shared__ __align__(16) _Float16 Al[4][128][8];
  __shared__ __align__(16) _Float16 Qs[4][64][8];    // [k/8][col][k%8]

  int tid = threadIdx.x;
  int lm  = tid >> 1;
  int kcA = (tid & 1) * 16;
  int lw  = tid >> 2;
  int kcW = (tid & 3) * 8;

  int am  = m0 + lm;
  int amc = XM ? ((am < mcount) ? am : (mcount - 1)) : am;
  int arow;
  if (XM == 1)      arow = tlist[mbase + amc];
  else if (XM == 2) arow = mbase + amc;
  else              arow = am;
  const float* Arow = A + (size_t)arow * lda;
  const float* Wrow = W + (size_t)(n0 + lw) * K;
  float wscale = sc[n0 + lw];

  int wv = tid >> 6, lane = tid & 63;
  int wm = wv >> 1, wn = wv & 1;
  int ks = lane >> 4, fr = lane & 15;

  f32x4 acch[4][2], accl[4][2];
  #pragma unroll
  for (int i = 0; i < 4; i++)
    #pragma unroll
    for (int j = 0; j < 2; j++) { acch[i][j] = (f32x4)0.f; accl[i][j] = (f32x4)0.f; }

  for (int kt = 0; kt < K; kt += 32) {
    float4 a0 = *reinterpret_cast<const float4*>(Arow + kt + kcA);
    float4 a1 = *reinterpret_cast<const float4*>(Arow + kt + kcA + 4);
    float4 a2 = *reinterpret_cast<const float4*>(Arow + kt + kcA + 8);
    float4 a3 = *reinterpret_cast<const float4*>(Arow + kt + kcA + 12);
    float av[16] = {a0.x,a0.y,a0.z,a0.w, a1.x,a1.y,a1.z,a1.w,
                    a2.x,a2.y,a2.z,a2.w, a3.x,a3.y,a3.z,a3.w};
    half8 h0, h1, l0, l1;
    #pragma unroll
    for (int j = 0; j < 8; j++) {
      _Float16 h = (_Float16)av[j];
      h0[j] = h; l0[j] = (_Float16)((av[j] - (float)h) * 2048.0f);
      _Float16 g = (_Float16)av[8 + j];
      h1[j] = g; l1[j] = (_Float16)((av[8 + j] - (float)g) * 2048.0f);
    }
    float4 w0 = *reinterpret_cast<const float4*>(Wrow + kt + kcW);
    float4 w1 = *reinterpret_cast<const float4*>(Wrow + kt + kcW + 4);
    float wvv[8] = {w0.x,w0.y,w0.z,w0.w, w1.x,w1.y,w1.z,w1.w};
    half8 qh;
    #pragma unroll
    for (int j = 0; j < 8; j++) {
      float qq = rintf(wvv[j] / wscale);
      qq = fminf(1.f, fmaxf(-1.f, qq));
      qh[j] = (_Float16)qq;
    }
    __syncthreads();
    int sA = kcA >> 3;
    *reinterpret_cast<half8*>(&Ah[sA][lm][0])     = h0;
    *reinterpret_cast<half8*>(&Ah[sA + 1][lm][0]) = h1;
    *reinterpret_cast<half8*>(&Al[sA][lm][0])     = l0;
    *reinterpret_cast<half8*>(&Al[sA + 1][lm][0]) = l1;
    *reinterpret_cast<half8*>(&Qs[kcW >> 3][lw][0]) = qh;
    __syncthreads();
    half8 bfr0 = *reinterpret_cast<half8*>(&Qs[ks][wn * 32 + fr][0]);
    half8 bfr1 = *reinterpret_cast<half8*>(&Qs[ks][wn * 32 + 16 + fr][0]);
    #pragma unroll
    for (int i = 0; i < 4; i++) {
      half8 ah = *reinterpret_cast<half8*>(&Ah[ks][wm * 64 + i * 16 + fr][0]);
      half8 al = *reinterpret_cast<half8*>(&Al[ks][wm * 64 + i * 16 + fr][0]);
      acch[i][0] = __builtin_amdgcn_mfma_f32_16x16x32_f16(ah, bfr0, acch[i][0], 0, 0, 0);
      acch[i][1] = __builtin_amdgcn_mfma_f32_16x16x32_f16(ah, bfr1, acch[i][1], 0, 0, 0);
      accl[i][0] = __builtin_amdgcn_mfma_f32_16x16x32_f16(al, bfr0, accl[i][0], 0, 0, 0);
      accl[i][1] = __builtin_amdgcn_mfma_f32_16x16x32_f16(al, bfr1, accl[i][1], 0, 0, 0);
    }
  }

  #pragma unroll
  for (int j = 0; j < 2; j++) {
    int col = n0 + wn * 32 + j * 16 + fr;
    float scl = sc[col];
    #pragma unroll
    for (int i = 0; i < 4; i++) {
      #pragma unroll
      for (int r = 0; r < 4; r++) {
        int lrow = m0 + wm * 64 + i * 16 + ks * 4 + r;
        if (XM && lrow >= mcount) continue;
        int orow;
        if (XM == 1)      orow = mbase + lrow;
        else if (XM == 2) orow = tlist[mbase + lrow];
        else              orow = lrow;
        float v = (acch[i][j][r] + accl[i][j][r] * (1.0f / 2048.0f)) * scl;
        if (EPI == 1) v = v * (1.0f / (1.0f + expf(-v)));
        else if (EPI == 2) v = res[(size_t)orow * ldc + col] + v;
        else if (EPI == 3) v = v * topp[orow];
        if (EPI == 5) {
          int bb = orow >> 10, tok = orow & 1023;
          Cout[((size_t)(bb << 10) + col) * 1024 + tok] = v;   // VT[b*1024+col][tok]
        } else {
          Cout[(size_t)orow * ldc + col] = v;
        }
      }
    }
  }
}

// ===== MFMA flash differential attention =====
// Block: one (b,h) x 64 q-rows; 4 waves x 16 rows. Online dual softmax.
// S = Qh*Kh + (Qh*Kl + Ql*Kh)/2048 ; O accum likewise (Oh + Ox/2048).
__global__ __launch_bounds__(256) void k_attn4(const float* __restrict__ q,
                                               const float* __restrict__ kk,
                                               const float* __restrict__ vt,
                                               const float* __restrict__ lamp,
                                               float* __restrict__ out)
{
  __shared__ __align__(16) _Float16 KH[2][64][72];
  __shared__ __align__(16) _Float16 KL[2][64][72];
  __shared__ __align__(16) _Float16 VH[64][72];    // [d][key]
  __shared__ __align__(16) _Float16 VL[64][72];
  __shared__ __align__(16) _Float16 PH[4][16][72]; // [wave][row][key]
  __shared__ __align__(16) _Float16 PL[4][16][72];

  int bh = blockIdx.x;
  int b = bh >> 4, h = bh & 15;
  int tq = blockIdx.y;
  int t0 = tq * 64;
  int tid = threadIdx.x;
  int wm = tid >> 6, lane = tid & 63;
  int ks = lane >> 4, fr = lane & 15;
  size_t tokbase = (size_t)b * T_;
  float lam = lamp[0];

  // ---- Q fragments (A layout): row = fr, k = s*32 + ks*8 + j ----
  half8 qh[2][2], ql[2][2];
  {
    const float* qr = q + (tokbase + t0 + wm * 16 + fr) * 2048 + h * 64;
    #pragma unroll
    for (int g = 0; g < 2; ++g)
      #pragma unroll
      for (int s = 0; s < 2; ++s) {
        const float* p = qr + g * 1024 + s * 32 + ks * 8;
        float4 x0 = *reinterpret_cast<const float4*>(p);
        float4 x1 = *reinterpret_cast<const float4*>(p + 4);
        float xv[8] = {x0.x,x0.y,x0.z,x0.w, x1.x,x1.y,x1.z,x1.w};
        half8 hh, ll;
        #pragma unroll
        for (int j = 0; j < 8; ++j) {
          _Float16 hv = (_Float16)xv[j];
          hh[j] = hv; ll[j] = (_Float16)((xv[j] - (float)hv) * 2048.0f);
        }
        qh[g][s] = hh; ql[g][s] = ll;
      }
  }

  f32x4 Oh[2][4], Ox[2][4];
  #pragma unroll
  for (int g = 0; g < 2; ++g)
    #pragma unroll
    for (int d = 0; d < 4; ++d) { Oh[g][d] = (f32x4)0.f; Ox[g][d] = (f32x4)0.f; }
  float mrun[2][4], lrun[2][4];
  #pragma unroll
  for (int g = 0; g < 2; ++g)
    #pragma unroll
    for (int r = 0; r < 4; ++r) { mrun[g][r] = -1e30f; lrun[g][r] = 0.f; }

  for (int jt = 0; jt <= tq; ++jt) {
    int kv0 = jt * 64;
    __syncthreads();
    // ---- stage K (both groups) ----
    {
      int key = tid & 63;
      int d0 = (tid >> 6) * 16;
      #pragma unroll
      for (int g = 0; g < 2; ++g) {
        const float* src = kk + (tokbase + kv0 + key) * 2048 + g * 1024 + h * 64 + d0;
        float4 a0 = *reinterpret_cast<const float4*>(src);
        float4 a1 = *reinterpret_cast<const float4*>(src + 4);
        float4 a2 = *reinterpret_cast<const float4*>(src + 8);
        float4 a3 = *reinterpret_cast<const float4*>(src + 12);
        float xv[16] = {a0.x,a0.y,a0.z,a0.w, a1.x,a1.y,a1.z,a1.w,
                        a2.x,a2.y,a2.z,a2.w, a3.x,a3.y,a3.z,a3.w};
        half8 h0, h1, l0, l1;
        #pragma unroll
        for (int j = 0; j < 8; ++j) {
          _Float16 hv = (_Float16)xv[j];
          h0[j] = hv; l0[j] = (_Float16)((xv[j] - (float)hv) * 2048.0f);
          _Float16 gv = (_Float16)xv[8 + j];
          h1[j] = gv; l1[j] = (_Float16)((xv[8 + j] - (float)gv) * 2048.0f);
        }
        *reinterpret_cast<half8*>(&KH[g][key][d0])     = h0;
        *reinterpret_cast<half8*>(&KH[g][key][d0 + 8]) = h1;
        *reinterpret_cast<half8*>(&KL[g][key][d0])     = l0;
        *reinterpret_cast<half8*>(&KL[g][key][d0 + 8]) = l1;
      }
      // ---- stage V (already transposed in global: VT[b*1024 + d][tok]) ----
      int dd = tid & 63;
      int k0 = (tid >> 6) * 16;
      const float* vsrc = vt + ((size_t)b * 1024 + h * 64 + dd) * 1024 + kv0 + k0;
      float4 a0 = *reinterpret_cast<const float4*>(vsrc);
      float4 a1 = *reinterpret_cast<const float4*>(vsrc + 4);
      float4 a2 = *reinterpret_cast<const float4*>(vsrc + 8);
      float4 a3 = *reinterpret_cast<const float4*>(vsrc + 12);
      float xv[16] = {a0.x,a0.y,a0.z,a0.w, a1.x,a1.y,a1.z,a1.w,
                      a2.x,a2.y,a2.z,a2.w, a3.x,a3.y,a3.z,a3.w};
      half8 h0, h1, l0, l1;
      #pragma unroll
      for (int j = 0; j < 8; ++j) {
        _Float16 hv = (_Float16)xv[j];
        h0[j] = hv; l0[j] = (_Float16)((xv[j] - (float)hv) * 2048.0f);
        _Float16 gv = (_Float16)xv[8 + j];
        h1[j] = gv; l1[j] = (_Float16)((xv[8 + j] - (float)gv) * 2048.0f);
      }
      *reinterpret_cast<half8*>(&VH[dd][k0])     = h0;
      *reinterpret_cast<half8*>(&VH[dd][k0 + 8]) = h1;
      *reinterpret_cast<half8*>(&VL[dd][k0])     = l0;
      *reinterpret_cast<half8*>(&VL[dd][k0 + 8]) = l1;
    }
    __syncthreads();

    bool diag = (jt == tq);
    #pragma unroll
    for (int g = 0; g < 2; ++g) {
      // ---- S strip = Q(16 rows) x K(64 keys) ----
      f32x4 Sh[4], Sx[4];
      #pragma unroll
      for (int kf = 0; kf < 4; ++kf) { Sh[kf] = (f32x4)0.f; Sx[kf] = (f32x4)0.f; }
      #pragma unroll
      for (int s = 0; s < 2; ++s) {
        #pragma unroll
        for (int kf = 0; kf < 4; ++kf) {
          half8 kh = *reinterpret_cast<half8*>(&KH[g][kf * 16 + fr][s * 32 + ks * 8]);
          half8 kl = *reinterpret_cast<half8*>(&KL[g][kf * 16 + fr][s * 32 + ks * 8]);
          Sh[kf] = __builtin_amdgcn_mfma_f32_16x16x32_f16(qh[g][s], kh, Sh[kf], 0, 0, 0);
          Sx[kf] = __builtin_amdgcn_mfma_f32_16x16x32_f16(qh[g][s], kl, Sx[kf], 0, 0, 0);
          Sx[kf] = __builtin_amdgcn_mfma_f32_16x16x32_f16(ql[g][s], kh, Sx[kf], 0, 0, 0);
        }
      }
      // f32 scores + causal mask; S elem: row = ks*4+r, col = kf*16+fr
      float sv[4][4];
      #pragma unroll
      for (int kf = 0; kf < 4; ++kf)
        #pragma unroll
        for (int r = 0; r < 4; ++r) {
          float s_ = (Sh[kf][r] + Sx[kf][r] * (1.0f / 2048.0f)) * 0.125f;
          if (diag) {
            int row_abs = t0 + wm * 16 + ks * 4 + r;
            int col_abs = kv0 + kf * 16 + fr;
            if (col_abs > row_abs) s_ = -1e30f;
          }
          sv[kf][r] = s_;
        }
      // online softmax per row r
      #pragma unroll
      for (int r = 0; r < 4; ++r) {
        float tmax = fmaxf(fmaxf(sv[0][r], sv[1][r]), fmaxf(sv[2][r], sv[3][r]));
        #pragma unroll
        for (int msk = 1; msk < 16; msk <<= 1) tmax = fmaxf(tmax, __shfl_xor(tmax, msk));
        float mnew = fmaxf(mrun[g][r], tmax);
        float scale = expf(mrun[g][r] - mnew);
        float e0 = expf(sv[0][r] - mnew);
        float e1 = expf(sv[1][r] - mnew);
        float e2 = expf(sv[2][r] - mnew);
        float e3 = expf(sv[3][r] - mnew);
        float rsum = (e0 + e1) + (e2 + e3);
        #pragma unroll
        for (int msk = 1; msk < 16; msk <<= 1) rsum += __shfl_xor(rsum, msk);
        lrun[g][r] = lrun[g][r] * scale + rsum;
        mrun[g][r] = mnew;
        #pragma unroll
        for (int df = 0; df < 4; ++df) { Oh[g][df][r] *= scale; Ox[g][df][r] *= scale; }
        // P split -> LDS (strip row = ks*4+r, key = kf*16+fr)
        float ev[4] = {e0, e1, e2, e3};
        #pragma unroll
        for (int kf = 0; kf < 4; ++kf) {
          _Float16 ph = (_Float16)ev[kf];
          _Float16 pl = (_Float16)((ev[kf] - (float)ph) * 2048.0f);
          PH[wm][ks * 4 + r][kf * 16 + fr] = ph;
          PL[wm][ks * 4 + r][kf * 16 + fr] = pl;
        }
      }
      // ---- PV: O += P(16x64) x Vt(64 d x 64 key) ----
      #pragma unroll
      for (int s = 0; s < 2; ++s) {
        half8 pah = *reinterpret_cast<half8*>(&PH[wm][fr][s * 32 + ks * 8]);
        half8 pal = *reinterpret_cast<half8*>(&PL[wm][fr][s * 32 + ks * 8]);
        #pragma unroll
        for (int df = 0; df < 4; ++df) {
          half8 vh = *reinterpret_cast<half8*>(&VH[df * 16 + fr][s * 32 + ks * 8]);
          half8 vl = *reinterpret_cast<half8*>(&VL[df * 16 + fr][s * 32 + ks * 8]);
          Oh[g][df] = __builtin_amdgcn_mfma_f32_16x16x32_f16(pah, vh, Oh[g][df], 0, 0, 0);
          Ox[g][df] = __builtin_amdgcn_mfma_f32_16x16x32_f16(pah, vl, Ox[g][df], 0, 0, 0);
          Ox[g][df] = __builtin_amdgcn_mfma_f32_16x16x32_f16(pal, vh, Ox[g][df], 0, 0, 0);
        }
      }
    }
  }

  // ---- finalize: out = O1/l1 - lam*O2/l2 ----
  #pragma unroll
  for (int df = 0; df < 4; ++df) {
    #pragma unroll
    for (int r = 0; r < 4; ++r) {
      int row_abs = t0 + wm * 16 + ks * 4 + r;
      int d = df * 16 + fr;
      float o1 = (Oh[0][df][r] + Ox[0][df][r] * (1.0f / 2048.0f)) / lrun[0][r];
      float o2 = (Oh[1][df][r] + Ox[1][df][r] * (1.0f / 2048.0f)) / lrun[1][r];
      out[(tokbase + row_abs) * 1024 + h * 64 + d] = o1 - lam * o2;
    }
  }
}

// ===== router: f32 fmaf logits, softmax over 8, first-max argmax =====
__global__ __launch_bounds__(256) void k_router(const float* __restrict__ hm,
                                                const float* __restrict__ rw,
                                                int* __restrict__ idx,
                                                float* __restrict__ topp)
{
  #pragma clang fp contract(off)
  int tid = threadIdx.x;
  int tg = tid >> 3, e = tid & 7;
  int m = blockIdx.x * 32 + tg;
  const float* hr = hm + (size_t)m * 1024;
  const float* wr = rw + (size_t)e * 1024;
  float l = 0.f;
  for (int dd = 0; dd < 1024; ++dd) l = __builtin_fmaf(hr[dd], wr[dd], l);
  float mx = l;
  #pragma unroll
  for (int off = 1; off < 8; off <<= 1) mx = fmaxf(mx, __shfl_xor(mx, off, 8));
  float p = expf(l - mx);
  float den = p;
  #pragma unroll
  for (int off = 1; off < 8; off <<= 1) den += __shfl_xor(den, off, 8);
  float prob = p / den;
  float pm = prob;
  #pragma unroll
  for (int off = 1; off < 8; off <<= 1) pm = fmaxf(pm, __shfl_xor(pm, off, 8));
  unsigned long long ball = __ballot(prob == pm);
  int grp = (tid & 63) >> 3;
  int first = __ffsll((unsigned long long)((ball >> (grp * 8)) & 0xFFull)) - 1;
  if (e == 0) { idx[m] = first; topp[m] = pm; }
}

// ===== deterministic token compaction (ballot prefix, token-ordered) =====
__global__ __launch_bounds__(512) void k_route_fill(const int* __restrict__ idx,
                                                    int* __restrict__ offs,
                                                    int* __restrict__ tlist)
{
  __shared__ int cnt[8];
  __shared__ int off[9];
  int w = threadIdx.x >> 6, lane = threadIdx.x & 63;
  int total = 0;
  for (int it = 0; it < M_ / 64; ++it) {
    int tok = it * 64 + lane;
    unsigned long long m = __ballot(idx[tok] == w);
    total += __popcll(m);
  }
  if (lane == 0) cnt[w] = total;
  __syncthreads();
  if (threadIdx.x == 0) {
    int o = 0;
    for (int e = 0; e < 8; ++e) { off[e] = o; o += cnt[e]; }
    off[8] = o;
    for (int e = 0; e < 9; ++e) offs[e] = off[e];
  }
  __syncthreads();
  int base = off[w];
  for (int it = 0; it < M_ / 64; ++it) {
    int tok = it * 64 + lane;
    bool sel = (idx[tok] == w);
    unsigned long long m = __ballot(sel);
    if (sel) {
      int pos = base + __popcll(m & ((1ull << lane) - 1ull));
      tlist[pos] = tok;
    }
    base += __popcll(m);
  }
}

// ===== final: x1 + (shared + routed) =====
__global__ __launch_bounds__(256) void k_final(const float* __restrict__ x1,
                                               const float* __restrict__ so,
                                               const float* __restrict__ rt,
                                               float* __restrict__ out) {
  #pragma clang fp contract(off)
  int i = blockIdx.x * 256 + threadIdx.x;
  float moe = so[i] + rt[i];
  out[i] = x1[i] + moe;
}

extern "C" void kernel_launch(void* const* d_in, const int* in_sizes, int n_in,
                              void* d_out, int out_size, void* d_ws, size_t ws_size,
                              hipStream_t stream) {
  const float* x   = (const float*)d_in[0];
  const float* Wq  = (const float*)d_in[2];
  const float* Wk  = (const float*)d_in[3];
  const float* Wv  = (const float*)d_in[4];
  const float* Wo  = (const float*)d_in[5];
  const float* lq  = (const float*)d_in[6];
  const float* lk  = (const float*)d_in[7];
  const float* qng = (const float*)d_in[8];
  const float* qnb = (const float*)d_in[9];
  const float* kng = (const float*)d_in[10];
  const float* knb = (const float*)d_in[11];
  const float* ag  = (const float*)d_in[12];
  const float* ab  = (const float*)d_in[13];
  const float* fg  = (const float*)d_in[14];
  const float* fb  = (const float*)d_in[15];
  const float* mg  = (const float*)d_in[16];
  const float* mb  = (const float*)d_in[17];
  const float* sw1 = (const float*)d_in[18];
  const float* sw2 = (const float*)d_in[19];
  const float* ew1 = (const float*)d_in[20];
  const float* ew2 = (const float*)d_in[21];
  const float* rw  = (const float*)d_in[22];

  float* ws = (float*)d_ws;
  size_t o = 0;
  float* scWq = ws + o; o += 2048;
  float* scWk = ws + o; o += 2048;
  float* scWv = ws + o; o += 1024;
  float* scWo = ws + o; o += 1024;
  float* scS1 = ws + o; o += 2048;
  float* scS2 = ws + o; o += 1024;
  float* scE1 = ws + o; o += 8 * 2048;
  float* scE2 = ws + o; o += 8 * 1024;
  float* lam  = ws + o; o += 16;
  float* TOPP = ws + o; o += 2048;
  int*   IDX  = (int*)(ws + o); o += 2048;
  int*   OFFS = (int*)(ws + o); o += 16;
  int*   TLIST= (int*)(ws + o); o += 2048;
  o = (o + 63) & ~(size_t)63;

  const size_t MQ = (size_t)M_ * 2048;
  const size_t MD = (size_t)M_ * 1024;
  float* R1 = ws + o;                 // QP -> (X1 | HM)
  float* R2 = ws + o + MQ;            // KP -> SM -> T1(compact)
  float* R3 = ws + o + 2 * MQ;        // VT -> SO
  float* R4 = ws + o + 2 * MQ + MD;   // H1 -> AO -> RT

  float* QP = R1;  float* X1 = R1;  float* HM = R1 + MD;
  float* KP = R2;  float* SM = R2;  float* T1 = R2;
  float* VT = R3;  float* SO = R3;
  float* H1 = R4;  float* AO = R4;  float* RT = R4;

  // scales + lambda
  k_scale<<<2048,     64, 0, stream>>>(Wq,  1024, scWq);
  k_scale<<<2048,     64, 0, stream>>>(Wk,  1024, scWk);
  k_scale<<<1024,     64, 0, stream>>>(Wv,  1024, scWv);
  k_scale<<<1024,     64, 0, stream>>>(Wo,  1024, scWo);
  k_scale<<<2048,     64, 0, stream>>>(sw1, 1024, scS1);
  k_scale<<<1024,     64, 0, stream>>>(sw2, 2048, scS2);
  k_scale<<<8 * 2048, 64, 0, stream>>>(ew1, 1024, scE1);
  k_scale<<<8 * 1024, 64, 0, stream>>>(ew2, 2048, scE2);
  k_lambda<<<1, 64, 0, stream>>>(lq, lk, lam);

  // attention block
  k_layernorm<<<M_, 256, 0, stream>>>(x, ag, ab, H1, 1024);
  k_mgemm<0,0><<<dim3(32,16), 256, 0, stream>>>(H1, 1024, Wq, scWq, QP, 2048, 2048, 1024, nullptr, nullptr, nullptr, nullptr);
  k_mgemm<0,0><<<dim3(32,16), 256, 0, stream>>>(H1, 1024, Wk, scWk, KP, 2048, 2048, 1024, nullptr, nullptr, nullptr, nullptr);
  k_mgemm<5,0><<<dim3(16,16), 256, 0, stream>>>(H1, 1024, Wv, scWv, VT, 1024, 1024, 1024, nullptr, nullptr, nullptr, nullptr);
  k_layernorm<<<M_, 256, 0, stream>>>(QP, qng, qnb, QP, 2048);
  k_layernorm<<<M_, 256, 0, stream>>>(KP, kng, knb, KP, 2048);
  k_attn4<<<dim3(32, 16), 256, 0, stream>>>(QP, KP, VT, lam, AO);   // AO over H1 (dead)
  k_mgemm<2,0><<<dim3(16,16), 256, 0, stream>>>(AO, 1024, Wo, scWo, X1, 1024, 1024, 1024, x, nullptr, nullptr, nullptr);

  // MoE block
  k_layernorm<<<M_, 256, 0, stream>>>(X1, fg, fb, HM, 1024);
  k_layernorm<<<M_, 256, 0, stream>>>(HM, mg, mb, HM, 1024);
  k_router<<<M_ / 32, 256, 0, stream>>>(HM, rw, IDX, TOPP);
  k_route_fill<<<1, 512, 0, stream>>>(IDX, OFFS, TLIST);

  // shared path
  k_mgemm<1,0><<<dim3(32,16), 256, 0, stream>>>(HM, 1024, sw1, scS1, SM, 2048, 2048, 1024, nullptr, nullptr, nullptr, nullptr);
  k_mgemm<0,0><<<dim3(16,16), 256, 0, stream>>>(SM, 2048, sw2, scS2, SO, 1024, 1024, 2048, nullptr, nullptr, nullptr, nullptr);

  // routed experts: SPARSE top-1
  k_mgemm<1,1><<<dim3(32,16,8), 256, 0, stream>>>(HM, 1024, ew1, scE1, T1, 2048, 2048, 1024, nullptr, OFFS, TLIST, nullptr);
  k_mgemm<3,2><<<dim3(16,16,8), 256, 0, stream>>>(T1, 2048, ew2, scE2, RT, 1024, 1024, 2048, nullptr, OFFS, TLIST, TOPP);

  k_final<<<8192, 256, 0, stream>>>(X1, SO, RT, (float*)d_out);
}

// Round 10
// 738.136 us; speedup vs baseline: 9.2882x; 1.1127x over previous
//
#include <hip/hip_runtime.h>
#include <hip/hip_bf16.h>

#define B_ 2
#define T_ 1024
#define D_ 1024
#define H_ 16
#define DH_ 64
#define F_ 2048
#define E_ 8
#define M_ 2048   // B*T tokens

typedef _Float16 half8 __attribute__((ext_vector_type(8)));
typedef float f32x4 __attribute__((ext_vector_type(4)));

// ===== numpy-style pairwise sum of a[0..K), K in {1024, 2048}, one wave =====
template<bool ABS>
__device__ __forceinline__ float np_pairwise_wave(const float* a, int K, int lane) {
  int nb = K >> 7;
  float s = 0.f;
  if (lane < nb) {
    const float* p = a + (lane << 7);
    float r[8];
    #pragma unroll
    for (int j = 0; j < 8; ++j) r[j] = ABS ? fabsf(p[j]) : p[j];
    for (int i = 8; i < 128; i += 8)
      #pragma unroll
      for (int j = 0; j < 8; ++j) r[j] += ABS ? fabsf(p[i + j]) : p[i + j];
    s = ((r[0] + r[1]) + (r[2] + r[3])) + ((r[4] + r[5]) + (r[6] + r[7]));
  }
  for (int off = 1; off < nb; off <<= 1) s += __shfl_xor(s, off);
  return __shfl(s, 0);
}

// ===== row scale: f32 mean(|W|) pairwise, clipped at 1e-5 =====
__global__ __launch_bounds__(64) void k_scale(const float* __restrict__ W, int K,
                                              float* __restrict__ out) {
  int r = blockIdx.x, lane = threadIdx.x;
  float S = np_pairwise_wave<true>(W + (size_t)r * K, K, lane);
  if (lane == 0) {
    float m = S / (float)K;
    out[r] = fmaxf(m, 1e-5f);
  }
}

// ===== pre-quantize weight row to ternary fp16 =====
__global__ __launch_bounds__(256) void k_prequant(const float* __restrict__ W,
                                                  const float* __restrict__ sc,
                                                  _Float16* __restrict__ out, int K) {
  int r = blockIdx.x;
  float s = sc[r];
  const float* src = W + (size_t)r * K;
  _Float16* dst = out + (size_t)r * K;
  for (int k = threadIdx.x * 4; k < K; k += 1024) {
    float4 w = *reinterpret_cast<const float4*>(src + k);
    float wv[4] = {w.x, w.y, w.z, w.w};
    #pragma unroll
    for (int j = 0; j < 4; ++j) {
      float q = rintf(wv[j] / s);
      q = fminf(1.f, fmaxf(-1.f, q));
      dst[k + j] = (_Float16)q;
    }
  }
}

// ===== lambda = clip(expf(mean(lq)-mean(lk)), 0.1, 2.0) =====
__global__ __launch_bounds__(64) void k_lambda(const float* __restrict__ lq,
                                               const float* __restrict__ lk,
                                               float* __restrict__ lam) {
  int lane = threadIdx.x;
  float mq = np_pairwise_wave<false>(lq, 1024, lane) / 1024.0f;
  float mk = np_pairwise_wave<false>(lk, 1024, lane) / 1024.0f;
  if (lane == 0) {
    float l = expf(mq - mk);
    lam[0] = fminf(2.0f, fmaxf(0.1f, l));
  }
}

// ===== layernorm f32->f32 (in==out allowed) =====
__global__ __launch_bounds__(256) void k_layernorm(const float* __restrict__ in,
                                                   const float* __restrict__ g,
                                                   const float* __restrict__ b,
                                                   float* __restrict__ out, int Dd) {
  #pragma clang fp contract(off)
  __shared__ float row[2048];
  __shared__ float sq[2048];
  __shared__ float stat[2];
  int m = blockIdx.x, tid = threadIdx.x;
  const float* src = in + (size_t)m * Dd;
  for (int d = tid; d < Dd; d += 256) row[d] = src[d];
  __syncthreads();
  if (tid < 64) {
    float S = np_pairwise_wave<false>(row, Dd, tid);
    if (tid == 0) stat[0] = S;
  }
  __syncthreads();
  float mean = stat[0] / (float)Dd;
  for (int d = tid; d < Dd; d += 256) { float t = row[d] - mean; sq[d] = t * t; }
  __syncthreads();
  if (tid < 64) {
    float S = np_pairwise_wave<false>(sq, Dd, tid);
    if (tid == 0) stat[1] = S;
  }
  __syncthreads();
  float var = stat[1] / (float)Dd;
  float rs = 1.0f / sqrtf(var + 1e-5f);
  float* dst = out + (size_t)m * Dd;
  for (int d = tid; d < Dd; d += 256) {
    float t = row[d] - mean;
    float u = t * rs;
    float v = u * g[d];
    dst[d] = v + b[d];
  }
}

// ===== layernorm f32 -> fp16 hi/lo split =====
__global__ __launch_bounds__(256) void k_layernorm_split(const float* __restrict__ in,
                                                         const float* __restrict__ g,
                                                         const float* __restrict__ b,
                                                         _Float16* __restrict__ oh,
                                                         _Float16* __restrict__ ol, int Dd) {
  #pragma clang fp contract(off)
  __shared__ float row[2048];
  __shared__ float sq[2048];
  __shared__ float stat[2];
  int m = blockIdx.x, tid = threadIdx.x;
  const float* src = in + (size_t)m * Dd;
  for (int d = tid; d < Dd; d += 256) row[d] = src[d];
  __syncthreads();
  if (tid < 64) {
    float S = np_pairwise_wave<false>(row, Dd, tid);
    if (tid == 0) stat[0] = S;
  }
  __syncthreads();
  float mean = stat[0] / (float)Dd;
  for (int d = tid; d < Dd; d += 256) { float t = row[d] - mean; sq[d] = t * t; }
  __syncthreads();
  if (tid < 64) {
    float S = np_pairwise_wave<false>(sq, Dd, tid);
    if (tid == 0) stat[1] = S;
  }
  __syncthreads();
  float var = stat[1] / (float)Dd;
  float rs = 1.0f / sqrtf(var + 1e-5f);
  #pragma unroll 1
  for (int d = tid; d < Dd; d += 256) {
    float t = row[d] - mean;
    float u = t * rs;
    float v = u * g[d];
    float w = v + b[d];
    _Float16 hv = (_Float16)w;
    oh[(size_t)m * Dd + d] = hv;
    ol[(size_t)m * Dd + d] = (_Float16)((w - (float)hv) * 2048.0f);
  }
}

// ===== fused double layernorm: LN(g1,b1) then LN(g2,b2); f32 + fp16-hi out =====
__global__ __launch_bounds__(256) void k_lnln(const float* __restrict__ in,
                                              const float* __restrict__ g1, const float* __restrict__ b1,
                                              const float* __restrict__ g2, const float* __restrict__ b2,
                                              float* __restrict__ outf,
                                              _Float16* __restrict__ outh) {
  #pragma clang fp contract(off)
  __shared__ float row[1024];
  __shared__ float tmp[1024];
  __shared__ float stat[2];
  int m = blockIdx.x, tid = threadIdx.x;
  const float* src = in + (size_t)m * 1024;
  for (int d = tid; d < 1024; d += 256) row[d] = src[d];
  __syncthreads();
  if (tid < 64) { float S = np_pairwise_wave<false>(row, 1024, tid); if (tid == 0) stat[0] = S; }
  __syncthreads();
  float mean = stat[0] / 1024.0f;
  for (int d = tid; d < 1024; d += 256) { float t = row[d] - mean; tmp[d] = t * t; }
  __syncthreads();
  if (tid < 64) { float S = np_pairwise_wave<false>(tmp, 1024, tid); if (tid == 0) stat[1] = S; }
  __syncthreads();
  float rs = 1.0f / sqrtf(stat[1] / 1024.0f + 1e-5f);
  for (int d = tid; d < 1024; d += 256) {
    float t = row[d] - mean;
    float u = t * rs;
    float v = u * g1[d];
    tmp[d] = v + b1[d];
  }
  __syncthreads();
  if (tid < 64) { float S = np_pairwise_wave<false>(tmp, 1024, tid); if (tid == 0) stat[0] = S; }
  __syncthreads();
  float mean2 = stat[0] / 1024.0f;
  for (int d = tid; d < 1024; d += 256) { float t = tmp[d] - mean2; row[d] = t * t; }
  __syncthreads();
  if (tid < 64) { float S = np_pairwise_wave<false>(row, 1024, tid); if (tid == 0) stat[1] = S; }
  __syncthreads();
  float rs2 = 1.0f / sqrtf(stat[1] / 1024.0f + 1e-5f);
  for (int d = tid; d < 1024; d += 256) {
    float t = tmp[d] - mean2;
    float u = t * rs2;
    float v = u * g2[d];
    float w = v + b2[d];
    outf[(size_t)m * 1024 + d] = w;
    outh[(size_t)m * 1024 + d] = (_Float16)w;
  }
}

// ===== MFMA GEMM with pre-split fp16 A and (optionally) pre-quantized fp16 W =====
// EPI: 0 f32 store, 1 silu->fp16-hi store, 2 res+ f32, 3 fused out=res+add2+v*topp, 5 VT store
// XM : 0 dense, 1 gather-in/compact-out, 2 compact-in/scatter-out
// DUAL: 1 = hi/lo error-compensated (router path), 0 = hi-only
// WQ : 1 = W pre-quantized fp16, 0 = quantize f32 W on the fly (experts)
template<int EPI, int XM, int DUAL, int WQ>
__global__ __launch_bounds__(256) void k_mgemm(
    const _Float16* __restrict__ Agh, const _Float16* __restrict__ Agl, int lda,
    const float* __restrict__ Wf, const _Float16* __restrict__ Wh,
    const float* __restrict__ scf,
    float* __restrict__ Cout, _Float16* __restrict__ Ch, int ldc, int N, int K,
    const float* __restrict__ res, const float* __restrict__ add2,
    const int* __restrict__ offs, const int* __restrict__ tlist,
    const float* __restrict__ topp)
{
  int e = XM ? blockIdx.z : 0;
  int mbase = 0, mcount = M_;
  const float* sc = scf;
  const float* Wfb = Wf;
  if (XM) {
    mbase = offs[e]; mcount = offs[e + 1] - mbase;
    if (!WQ) Wfb = Wf + (size_t)e * N * K;
    sc = scf + (size_t)e * N;
  }
  int m0 = blockIdx.y * 128;
  if (XM && m0 >= mcount) return;
  int n0 = blockIdx.x * 64;

  __shared__ __align__(16) _Float16 As[4][128][8];
  __shared__ __align__(16) _Float16 Als[DUAL ? 4 : 1][128][8];
  __shared__ __align__(16) _Float16 Qs[4][64][8];

  int tid = threadIdx.x;
  int lm  = tid >> 1;
  int kcA = (tid & 1) * 16;
  int lw  = tid >> 2;
  int kcW = (tid & 3) * 8;

  int am  = m0 + lm;
  int amc = XM ? ((am < mcount) ? am : (mcount - 1)) : am;
  int arow;
  if (XM == 1)      arow = tlist[mbase + amc];
  else if (XM == 2) arow = mbase + amc;
  else              arow = am;
  const _Float16* Arh = Agh + (size_t)arow * lda;
  const _Float16* Arl = DUAL ? (Agl + (size_t)arow * lda) : nullptr;
  const float*    Wrf = WQ ? nullptr : (Wfb + (size_t)(n0 + lw) * K);
  const _Float16* Wrh = WQ ? (Wh + (size_t)(n0 + lw) * K) : nullptr;
  float wscale = WQ ? 0.f : sc[n0 + lw];

  int wv = tid >> 6, lane = tid & 63;
  int wm = wv >> 1, wn = wv & 1;
  int ks = lane >> 4, fr = lane & 15;

  f32x4 acch[4][2], accl[4][2];
  #pragma unroll
  for (int i = 0; i < 4; i++)
    #pragma unroll
    for (int j = 0; j < 2; j++) { acch[i][j] = (f32x4)0.f; accl[i][j] = (f32x4)0.f; }

  for (int kt = 0; kt < K; kt += 32) {
    half8 a0 = *reinterpret_cast<const half8*>(Arh + kt + kcA);
    half8 a1 = *reinterpret_cast<const half8*>(Arh + kt + kcA + 8);
    half8 b0, b1;
    if (DUAL) {
      b0 = *reinterpret_cast<const half8*>(Arl + kt + kcA);
      b1 = *reinterpret_cast<const half8*>(Arl + kt + kcA + 8);
    }
    half8 qv;
    if (WQ) {
      qv = *reinterpret_cast<const half8*>(Wrh + kt + kcW);
    } else {
      float4 w0 = *reinterpret_cast<const float4*>(Wrf + kt + kcW);
      float4 w1 = *reinterpret_cast<const float4*>(Wrf + kt + kcW + 4);
      float wvv[8] = {w0.x,w0.y,w0.z,w0.w, w1.x,w1.y,w1.z,w1.w};
      #pragma unroll
      for (int j = 0; j < 8; j++) {
        float qq = rintf(wvv[j] / wscale);
        qq = fminf(1.f, fmaxf(-1.f, qq));
        qv[j] = (_Float16)qq;
      }
    }
    __syncthreads();
    int sA = kcA >> 3;
    *reinterpret_cast<half8*>(&As[sA][lm][0])     = a0;
    *reinterpret_cast<half8*>(&As[sA + 1][lm][0]) = a1;
    if (DUAL) {
      *reinterpret_cast<half8*>(&Als[sA][lm][0])     = b0;
      *reinterpret_cast<half8*>(&Als[sA + 1][lm][0]) = b1;
    }
    *reinterpret_cast<half8*>(&Qs[kcW >> 3][lw][0]) = qv;
    __syncthreads();
    half8 bfr0 = *reinterpret_cast<half8*>(&Qs[ks][wn * 32 + fr][0]);
    half8 bfr1 = *reinterpret_cast<half8*>(&Qs[ks][wn * 32 + 16 + fr][0]);
    #pragma unroll
    for (int i = 0; i < 4; i++) {
      half8 ah = *reinterpret_cast<half8*>(&As[ks][wm * 64 + i * 16 + fr][0]);
      acch[i][0] = __builtin_amdgcn_mfma_f32_16x16x32_f16(ah, bfr0, acch[i][0], 0, 0, 0);
      acch[i][1] = __builtin_amdgcn_mfma_f32_16x16x32_f16(ah, bfr1, acch[i][1], 0, 0, 0);
      if (DUAL) {
        half8 al = *reinterpret_cast<half8*>(&Als[ks][wm * 64 + i * 16 + fr][0]);
        accl[i][0] = __builtin_amdgcn_mfma_f32_16x16x32_f16(al, bfr0, accl[i][0], 0, 0, 0);
        accl[i][1] = __builtin_amdgcn_mfma_f32_16x16x32_f16(al, bfr1, accl[i][1], 0, 0, 0);
      }
    }
  }

  #pragma unroll
  for (int j = 0; j < 2; j++) {
    int col = n0 + wn * 32 + j * 16 + fr;
    float scl = sc[col];
    #pragma unroll
    for (int i = 0; i < 4; i++) {
      #pragma unroll
      for (int r = 0; r < 4; r++) {
        int lrow = m0 + wm * 64 + i * 16 + ks * 4 + r;
        if (XM && lrow >= mcount) continue;
        int orow;
        if (XM == 1)      orow = mbase + lrow;
        else if (XM == 2) orow = tlist[mbase + lrow];
        else              orow = lrow;
        float v = acch[i][j][r];
        if (DUAL) v += accl[i][j][r] * (1.0f / 2048.0f);
        v *= scl;
        if (EPI == 1) {
          v = v * (1.0f / (1.0f + expf(-v)));
          Ch[(size_t)orow * ldc + col] = (_Float16)v;
        } else if (EPI == 3) {
          float rt = v * topp[orow];
          float moe = add2[(size_t)orow * ldc + col] + rt;
          Cout[(size_t)orow * ldc + col] = res[(size_t)orow * ldc + col] + moe;
        } else if (EPI == 5) {
          int bb = orow >> 10, tok = orow & 1023;
          Cout[((size_t)(bb << 10) + col) * 1024 + tok] = v;
        } else if (EPI == 2) {
          Cout[(size_t)orow * ldc + col] = res[(size_t)orow * ldc + col] + v;
        } else {
          Cout[(size_t)orow * ldc + col] = v;
        }
      }
    }
  }
}

// ===== MFMA flash differential attention (split epilogue + defer-rescale) =====
__global__ __launch_bounds__(256) void k_attn4(const float* __restrict__ q,
                                               const float* __restrict__ kk,
                                               const float* __restrict__ vt,
                                               const float* __restrict__ lamp,
                                               _Float16* __restrict__ aoh,
                                               _Float16* __restrict__ aol)
{
  __shared__ __align__(16) _Float16 KH[2][64][72];
  __shared__ __align__(16) _Float16 KL[2][64][72];
  __shared__ __align__(16) _Float16 VH[64][72];
  __shared__ __align__(16) _Float16 VL[64][72];
  __shared__ __align__(16) _Float16 PH[4][16][72];
  __shared__ __align__(16) _Float16 PL[4][16][72];

  int bh = blockIdx.x;
  int b = bh >> 4, h = bh & 15;
  int tq = blockIdx.y;
  int t0 = tq * 64;
  int tid = threadIdx.x;
  int wm = tid >> 6, lane = tid & 63;
  int ks = lane >> 4, fr = lane & 15;
  size_t tokbase = (size_t)b * T_;
  float lam = lamp[0];

  half8 qh[2][2], ql[2][2];
  {
    const float* qr = q + (tokbase + t0 + wm * 16 + fr) * 2048 + h * 64;
    #pragma unroll
    for (int g = 0; g < 2; ++g)
      #pragma unroll
      for (int s = 0; s < 2; ++s) {
        const float* p = qr + g * 1024 + s * 32 + ks * 8;
        float4 x0 = *reinterpret_cast<const float4*>(p);
        float4 x1 = *reinterpret_cast<const float4*>(p + 4);
        float xv[8] = {x0.x,x0.y,x0.z,x0.w, x1.x,x1.y,x1.z,x1.w};
        half8 hh, ll;
        #pragma unroll
        for (int j = 0; j < 8; ++j) {
          _Float16 hv = (_Float16)xv[j];
          hh[j] = hv; ll[j] = (_Float16)((xv[j] - (float)hv) * 2048.0f);
        }
        qh[g][s] = hh; ql[g][s] = ll;
      }
  }

  f32x4 Oh[2][4], Ox[2][4];
  #pragma unroll
  for (int g = 0; g < 2; ++g)
    #pragma unroll
    for (int d = 0; d < 4; ++d) { Oh[g][d] = (f32x4)0.f; Ox[g][d] = (f32x4)0.f; }
  float mrun[2][4], lrun[2][4];
  #pragma unroll
  for (int g = 0; g < 2; ++g)
    #pragma unroll
    for (int r = 0; r < 4; ++r) { mrun[g][r] = -1e30f; lrun[g][r] = 0.f; }

  for (int jt = 0; jt <= tq; ++jt) {
    int kv0 = jt * 64;
    __syncthreads();
    {
      int key = tid & 63;
      int d0 = (tid >> 6) * 16;
      #pragma unroll
      for (int g = 0; g < 2; ++g) {
        const float* src = kk + (tokbase + kv0 + key) * 2048 + g * 1024 + h * 64 + d0;
        float4 a0 = *reinterpret_cast<const float4*>(src);
        float4 a1 = *reinterpret_cast<const float4*>(src + 4);
        float4 a2 = *reinterpret_cast<const float4*>(src + 8);
        float4 a3 = *reinterpret_cast<const float4*>(src + 12);
        float xv[16] = {a0.x,a0.y,a0.z,a0.w, a1.x,a1.y,a1.z,a1.w,
                        a2.x,a2.y,a2.z,a2.w, a3.x,a3.y,a3.z,a3.w};
        half8 h0, h1, l0, l1;
        #pragma unroll
        for (int j = 0; j < 8; ++j) {
          _Float16 hv = (_Float16)xv[j];
          h0[j] = hv; l0[j] = (_Float16)((xv[j] - (float)hv) * 2048.0f);
          _Float16 gv = (_Float16)xv[8 + j];
          h1[j] = gv; l1[j] = (_Float16)((xv[8 + j] - (float)gv) * 2048.0f);
        }
        *reinterpret_cast<half8*>(&KH[g][key][d0])     = h0;
        *reinterpret_cast<half8*>(&KH[g][key][d0 + 8]) = h1;
        *reinterpret_cast<half8*>(&KL[g][key][d0])     = l0;
        *reinterpret_cast<half8*>(&KL[g][key][d0 + 8]) = l1;
      }
      int dd = tid & 63;
      int k0 = (tid >> 6) * 16;
      const float* vsrc = vt + ((size_t)b * 1024 + h * 64 + dd) * 1024 + kv0 + k0;
      float4 a0 = *reinterpret_cast<const float4*>(vsrc);
      float4 a1 = *reinterpret_cast<const float4*>(vsrc + 4);
      float4 a2 = *reinterpret_cast<const float4*>(vsrc + 8);
      float4 a3 = *reinterpret_cast<const float4*>(vsrc + 12);
      float xv[16] = {a0.x,a0.y,a0.z,a0.w, a1.x,a1.y,a1.z,a1.w,
                      a2.x,a2.y,a2.z,a2.w, a3.x,a3.y,a3.z,a3.w};
      half8 h0, h1, l0, l1;
      #pragma unroll
      for (int j = 0; j < 8; ++j) {
        _Float16 hv = (_Float16)xv[j];
        h0[j] = hv; l0[j] = (_Float16)((xv[j] - (float)hv) * 2048.0f);
        _Float16 gv = (_Float16)xv[8 + j];
        h1[j] = gv; l1[j] = (_Float16)((xv[8 + j] - (float)gv) * 2048.0f);
      }
      *reinterpret_cast<half8*>(&VH[dd][k0])     = h0;
      *reinterpret_cast<half8*>(&VH[dd][k0 + 8]) = h1;
      *reinterpret_cast<half8*>(&VL[dd][k0])     = l0;
      *reinterpret_cast<half8*>(&VL[dd][k0 + 8]) = l1;
    }
    __syncthreads();

    bool diag = (jt == tq);
    #pragma unroll
    for (int g = 0; g < 2; ++g) {
      f32x4 Sh[4], Sx[4];
      #pragma unroll
      for (int kf = 0; kf < 4; ++kf) { Sh[kf] = (f32x4)0.f; Sx[kf] = (f32x4)0.f; }
      #pragma unroll
      for (int s = 0; s < 2; ++s) {
        #pragma unroll
        for (int kf = 0; kf < 4; ++kf) {
          half8 kh = *reinterpret_cast<half8*>(&KH[g][kf * 16 + fr][s * 32 + ks * 8]);
          half8 kl = *reinterpret_cast<half8*>(&KL[g][kf * 16 + fr][s * 32 + ks * 8]);
          Sh[kf] = __builtin_amdgcn_mfma_f32_16x16x32_f16(qh[g][s], kh, Sh[kf], 0, 0, 0);
          Sx[kf] = __builtin_amdgcn_mfma_f32_16x16x32_f16(qh[g][s], kl, Sx[kf], 0, 0, 0);
          Sx[kf] = __builtin_amdgcn_mfma_f32_16x16x32_f16(ql[g][s], kh, Sx[kf], 0, 0, 0);
        }
      }
      float sv[4][4];
      #pragma unroll
      for (int kf = 0; kf < 4; ++kf)
        #pragma unroll
        for (int r = 0; r < 4; ++r) {
          float s_ = (Sh[kf][r] + Sx[kf][r] * (1.0f / 2048.0f)) * 0.125f;
          if (diag) {
            int row_abs = t0 + wm * 16 + ks * 4 + r;
            int col_abs = kv0 + kf * 16 + fr;
            if (col_abs > row_abs) s_ = -1e30f;
          }
          sv[kf][r] = s_;
        }
      #pragma unroll
      for (int r = 0; r < 4; ++r) {
        float tmax = fmaxf(fmaxf(sv[0][r], sv[1][r]), fmaxf(sv[2][r], sv[3][r]));
        #pragma unroll
        for (int msk = 1; msk < 16; msk <<= 1) tmax = fmaxf(tmax, __shfl_xor(tmax, msk));
        bool up = tmax > mrun[g][r];
        float mnew = up ? tmax : mrun[g][r];
        float e0 = expf(sv[0][r] - mnew);
        float e1 = expf(sv[1][r] - mnew);
        float e2 = expf(sv[2][r] - mnew);
        float e3 = expf(sv[3][r] - mnew);
        float rsum = (e0 + e1) + (e2 + e3);
        #pragma unroll
        for (int msk = 1; msk < 16; msk <<= 1) rsum += __shfl_xor(rsum, msk);
        if (up) {
          float scale = expf(mrun[g][r] - tmax);
          lrun[g][r] = lrun[g][r] * scale + rsum;
          mrun[g][r] = tmax;
          #pragma unroll
          for (int df = 0; df < 4; ++df) { Oh[g][df][r] *= scale; Ox[g][df][r] *= scale; }
        } else {
          lrun[g][r] += rsum;
        }
        float ev[4] = {e0, e1, e2, e3};
        #pragma unroll
        for (int kf = 0; kf < 4; ++kf) {
          _Float16 ph = (_Float16)ev[kf];
          _Float16 pl = (_Float16)((ev[kf] - (float)ph) * 2048.0f);
          PH[wm][ks * 4 + r][kf * 16 + fr] = ph;
          PL[wm][ks * 4 + r][kf * 16 + fr] = pl;
        }
      }
      #pragma unroll
      for (int s = 0; s < 2; ++s) {
        half8 pah = *reinterpret_cast<half8*>(&PH[wm][fr][s * 32 + ks * 8]);
        half8 pal = *reinterpret_cast<half8*>(&PL[wm][fr][s * 32 + ks * 8]);
        #pragma unroll
        for (int df = 0; df < 4; ++df) {
          half8 vh = *reinterpret_cast<half8*>(&VH[df * 16 + fr][s * 32 + ks * 8]);
          half8 vl = *reinterpret_cast<half8*>(&VL[df * 16 + fr][s * 32 + ks * 8]);
          Oh[g][df] = __builtin_amdgcn_mfma_f32_16x16x32_f16(pah, vh, Oh[g][df], 0, 0, 0);
          Ox[g][df] = __builtin_amdgcn_mfma_f32_16x16x32_f16(pah, vl, Ox[g][df], 0, 0, 0);
          Ox[g][df] = __builtin_amdgcn_mfma_f32_16x16x32_f16(pal, vh, Ox[g][df], 0, 0, 0);
        }
      }
    }
  }

  #pragma unroll
  for (int df = 0; df < 4; ++df) {
    #pragma unroll
    for (int r = 0; r < 4; ++r) {
      int row_abs = t0 + wm * 16 + ks * 4 + r;
      int d = df * 16 + fr;
      float o1 = (Oh[0][df][r] + Ox[0][df][r] * (1.0f / 2048.0f)) / lrun[0][r];
      float o2 = (Oh[1][df][r] + Ox[1][df][r] * (1.0f / 2048.0f)) / lrun[1][r];
      float oo = o1 - lam * o2;
      size_t idx = (tokbase + row_abs) * 1024 + h * 64 + d;
      _Float16 hv = (_Float16)oo;
      aoh[idx] = hv;
      aol[idx] = (_Float16)((oo - (float)hv) * 2048.0f);
    }
  }
}

// ===== router =====
__global__ __launch_bounds__(256) void k_router(const float* __restrict__ hm,
                                                const float* __restrict__ rw,
                                                int* __restrict__ idx,
                                                float* __restrict__ topp)
{
  #pragma clang fp contract(off)
  int tid = threadIdx.x;
  int tg = tid >> 3, e = tid & 7;
  int m = blockIdx.x * 32 + tg;
  const float* hr = hm + (size_t)m * 1024;
  const float* wr = rw + (size_t)e * 1024;
  float l = 0.f;
  for (int dd = 0; dd < 1024; ++dd) l = __builtin_fmaf(hr[dd], wr[dd], l);
  float mx = l;
  #pragma unroll
  for (int off = 1; off < 8; off <<= 1) mx = fmaxf(mx, __shfl_xor(mx, off, 8));
  float p = expf(l - mx);
  float den = p;
  #pragma unroll
  for (int off = 1; off < 8; off <<= 1) den += __shfl_xor(den, off, 8);
  float prob = p / den;
  float pm = prob;
  #pragma unroll
  for (int off = 1; off < 8; off <<= 1) pm = fmaxf(pm, __shfl_xor(pm, off, 8));
  unsigned long long ball = __ballot(prob == pm);
  int grp = (tid & 63) >> 3;
  int first = __ffsll((unsigned long long)((ball >> (grp * 8)) & 0xFFull)) - 1;
  if (e == 0) { idx[m] = first; topp[m] = pm; }
}

// ===== deterministic token compaction =====
__global__ __launch_bounds__(512) void k_route_fill(const int* __restrict__ idx,
                                                    int* __restrict__ offs,
                                                    int* __restrict__ tlist)
{
  __shared__ int cnt[8];
  __shared__ int off[9];
  int w = threadIdx.x >> 6, lane = threadIdx.x & 63;
  int total = 0;
  for (int it = 0; it < M_ / 64; ++it) {
    int tok = it * 64 + lane;
    unsigned long long m = __ballot(idx[tok] == w);
    total += __popcll(m);
  }
  if (lane == 0) cnt[w] = total;
  __syncthreads();
  if (threadIdx.x == 0) {
    int o = 0;
    for (int e = 0; e < 8; ++e) { off[e] = o; o += cnt[e]; }
    off[8] = o;
    for (int e = 0; e < 9; ++e) offs[e] = off[e];
  }
  __syncthreads();
  int base = off[w];
  for (int it = 0; it < M_ / 64; ++it) {
    int tok = it * 64 + lane;
    bool sel = (idx[tok] == w);
    unsigned long long m = __ballot(sel);
    if (sel) {
      int pos = base + __popcll(m & ((1ull << lane) - 1ull));
      tlist[pos] = tok;
    }
    base += __popcll(m);
  }
}

extern "C" void kernel_launch(void* const* d_in, const int* in_sizes, int n_in,
                              void* d_out, int out_size, void* d_ws, size_t ws_size,
                              hipStream_t stream) {
  const float* x   = (const float*)d_in[0];
  const float* Wq  = (const float*)d_in[2];
  const float* Wk  = (const float*)d_in[3];
  const float* Wv  = (const float*)d_in[4];
  const float* Wo  = (const float*)d_in[5];
  const float* lq  = (const float*)d_in[6];
  const float* lk  = (const float*)d_in[7];
  const float* qng = (const float*)d_in[8];
  const float* qnb = (const float*)d_in[9];
  const float* kng = (const float*)d_in[10];
  const float* knb = (const float*)d_in[11];
  const float* ag  = (const float*)d_in[12];
  const float* ab  = (const float*)d_in[13];
  const float* fg  = (const float*)d_in[14];
  const float* fb  = (const float*)d_in[15];
  const float* mg  = (const float*)d_in[16];
  const float* mb  = (const float*)d_in[17];
  const float* sw1 = (const float*)d_in[18];
  const float* sw2 = (const float*)d_in[19];
  const float* ew1 = (const float*)d_in[20];
  const float* ew2 = (const float*)d_in[21];
  const float* rw  = (const float*)d_in[22];

  float* ws = (float*)d_ws;
  size_t o = 0;
  float* scWq = ws + o; o += 2048;
  float* scWk = ws + o; o += 2048;
  float* scWv = ws + o; o += 1024;
  float* scWo = ws + o; o += 1024;
  float* scS1 = ws + o; o += 2048;
  float* scS2 = ws + o; o += 1024;
  float* scE1 = ws + o; o += 8 * 2048;
  float* scE2 = ws + o; o += 8 * 1024;
  float* lam  = ws + o; o += 16;
  float* TOPP = ws + o; o += 2048;
  int*   IDX  = (int*)(ws + o); o += 2048;
  int*   OFFS = (int*)(ws + o); o += 16;
  int*   TLIST= (int*)(ws + o); o += 2048;
  o = (o + 15) & ~(size_t)15;

  // pre-quantized fp16 dense weights (f32-unit sizes = halves/2)
  _Float16* QWq = (_Float16*)(ws + o); o += 1024 * 1024;      // 2048x1024 halves
  _Float16* QWk = (_Float16*)(ws + o); o += 1024 * 1024;
  _Float16* QWv = (_Float16*)(ws + o); o += 512 * 1024;       // 1024x1024 halves
  _Float16* QWo = (_Float16*)(ws + o); o += 512 * 1024;
  _Float16* QS1 = (_Float16*)(ws + o); o += 1024 * 1024;
  _Float16* QS2 = (_Float16*)(ws + o); o += 1024 * 1024;      // 1024x2048 halves

  // split region A: H1h+H1l (2x 2M halves) -> SMh (4M halves) -> T1h (4M halves)
  float* RA = ws + o; o += 2 * 1024 * 1024;
  _Float16* H1h = (_Float16*)RA;
  _Float16* H1l = (_Float16*)(RA + 1024 * 1024);
  _Float16* SMh = (_Float16*)RA;
  _Float16* T1h = (_Float16*)RA;
  // split region B: AOh+AOl -> HMh
  float* RB = ws + o; o += 2 * 1024 * 1024;
  _Float16* AOh = (_Float16*)RB;
  _Float16* AOl = (_Float16*)(RB + 1024 * 1024);
  _Float16* HMh = (_Float16*)RB;

  const size_t MQ = (size_t)M_ * 2048;
  const size_t MD = (size_t)M_ * 1024;
  float* QP = ws + o; o += MQ;          // -> X1 | HM after attention
  float* KP = ws + o; o += MQ;          // -> SO after attention
  float* VT = ws + o; o += MD;          // dead after attention

  float* X1 = QP;
  float* HM = QP + MD;
  float* SO = KP;

  // scales + lambda + prequant
  k_scale<<<2048,     64, 0, stream>>>(Wq,  1024, scWq);
  k_scale<<<2048,     64, 0, stream>>>(Wk,  1024, scWk);
  k_scale<<<1024,     64, 0, stream>>>(Wv,  1024, scWv);
  k_scale<<<1024,     64, 0, stream>>>(Wo,  1024, scWo);
  k_scale<<<2048,     64, 0, stream>>>(sw1, 1024, scS1);
  k_scale<<<1024,     64, 0, stream>>>(sw2, 2048, scS2);
  k_scale<<<8 * 2048, 64, 0, stream>>>(ew1, 1024, scE1);
  k_scale<<<8 * 1024, 64, 0, stream>>>(ew2, 2048, scE2);
  k_lambda<<<1, 64, 0, stream>>>(lq, lk, lam);
  k_prequant<<<2048, 256, 0, stream>>>(Wq,  scWq, QWq, 1024);
  k_prequant<<<2048, 256, 0, stream>>>(Wk,  scWk, QWk, 1024);
  k_prequant<<<1024, 256, 0, stream>>>(Wv,  scWv, QWv, 1024);
  k_prequant<<<1024, 256, 0, stream>>>(Wo,  scWo, QWo, 1024);
  k_prequant<<<2048, 256, 0, stream>>>(sw1, scS1, QS1, 1024);
  k_prequant<<<1024, 256, 0, stream>>>(sw2, scS2, QS2, 2048);

  // attention block (router path: DUAL, bitwise-identical to round 9)
  k_layernorm_split<<<M_, 256, 0, stream>>>(x, ag, ab, H1h, H1l, 1024);
  k_mgemm<0,0,1,1><<<dim3(32,16), 256, 0, stream>>>(H1h, H1l, 1024, nullptr, QWq, scWq, QP, nullptr, 2048, 2048, 1024, nullptr, nullptr, nullptr, nullptr, nullptr);
  k_mgemm<0,0,1,1><<<dim3(32,16), 256, 0, stream>>>(H1h, H1l, 1024, nullptr, QWk, scWk, KP, nullptr, 2048, 2048, 1024, nullptr, nullptr, nullptr, nullptr, nullptr);
  k_mgemm<5,0,1,1><<<dim3(16,16), 256, 0, stream>>>(H1h, H1l, 1024, nullptr, QWv, scWv, VT, nullptr, 1024, 1024, 1024, nullptr, nullptr, nullptr, nullptr, nullptr);
  k_layernorm<<<M_, 256, 0, stream>>>(QP, qng, qnb, QP, 2048);
  k_layernorm<<<M_, 256, 0, stream>>>(KP, kng, knb, KP, 2048);
  k_attn4<<<dim3(32, 16), 256, 0, stream>>>(QP, KP, VT, lam, AOh, AOl);
  k_mgemm<2,0,1,1><<<dim3(16,16), 256, 0, stream>>>(AOh, AOl, 1024, nullptr, QWo, scWo, X1, nullptr, 1024, 1024, 1024, x, nullptr, nullptr, nullptr, nullptr);

  // MoE block
  k_lnln<<<M_, 256, 0, stream>>>(X1, fg, fb, mg, mb, HM, HMh);
  k_router<<<M_ / 32, 256, 0, stream>>>(HM, rw, IDX, TOPP);
  k_route_fill<<<1, 512, 0, stream>>>(IDX, OFFS, TLIST);

  // shared path (single-pass hi-only, downstream of router)
  k_mgemm<1,0,0,1><<<dim3(32,16), 256, 0, stream>>>(HMh, nullptr, 1024, nullptr, QS1, scS1, nullptr, SMh, 2048, 2048, 1024, nullptr, nullptr, nullptr, nullptr, nullptr);
  k_mgemm<0,0,0,1><<<dim3(16,16), 256, 0, stream>>>(SMh, nullptr, 2048, nullptr, QS2, scS2, SO, nullptr, 1024, 1024, 2048, nullptr, nullptr, nullptr, nullptr, nullptr);

  // routed experts (sparse top-1, single-pass; final add fused into scatter)
  k_mgemm<1,1,0,0><<<dim3(32,16,8), 256, 0, stream>>>(HMh, nullptr, 1024, ew1, nullptr, scE1, nullptr, T1h, 2048, 2048, 1024, nullptr, nullptr, OFFS, TLIST, nullptr);
  k_mgemm<3,2,0,0><<<dim3(16,16,8), 256, 0, stream>>>(T1h, nullptr, 2048, ew2, nullptr, scE2, (float*)d_out, nullptr, 1024, 1024, 2048, X1, SO, OFFS, TLIST, TOPP);
}

// Round 11
// 688.859 us; speedup vs baseline: 9.9527x; 1.0715x over previous
//
#include <hip/hip_runtime.h>
#include <hip/hip_bf16.h>

#define B_ 2
#define T_ 1024
#define D_ 1024
#define H_ 16
#define DH_ 64
#define F_ 2048
#define E_ 8
#define M_ 2048   // B*T tokens

typedef _Float16 half8 __attribute__((ext_vector_type(8)));
typedef _Float16 half4v __attribute__((ext_vector_type(4)));
typedef float f32x4 __attribute__((ext_vector_type(4)));

// ===== numpy-style pairwise sum of a[0..K), K in {1024, 2048}, one wave =====
template<bool ABS>
__device__ __forceinline__ float np_pairwise_wave(const float* a, int K, int lane) {
  int nb = K >> 7;
  float s = 0.f;
  if (lane < nb) {
    const float* p = a + (lane << 7);
    float r[8];
    #pragma unroll
    for (int j = 0; j < 8; ++j) r[j] = ABS ? fabsf(p[j]) : p[j];
    for (int i = 8; i < 128; i += 8)
      #pragma unroll
      for (int j = 0; j < 8; ++j) r[j] += ABS ? fabsf(p[i + j]) : p[i + j];
    s = ((r[0] + r[1]) + (r[2] + r[3])) + ((r[4] + r[5]) + (r[6] + r[7]));
  }
  for (int off = 1; off < nb; off <<= 1) s += __shfl_xor(s, off);
  return __shfl(s, 0);
}

// ===== row scale only (experts) =====
__global__ __launch_bounds__(64) void k_scale(const float* __restrict__ W, int K,
                                              float* __restrict__ out) {
  int r = blockIdx.x, lane = threadIdx.x;
  float S = np_pairwise_wave<true>(W + (size_t)r * K, K, lane);
  if (lane == 0) out[r] = fmaxf(S / (float)K, 1e-5f);
}

// ===== fused scale + prequant (dense weights): one read of W =====
__global__ __launch_bounds__(64) void k_scaleq(const float* __restrict__ W, int K,
                                               float* __restrict__ scOut,
                                               _Float16* __restrict__ qOut) {
  int r = blockIdx.x, lane = threadIdx.x;
  const float* row = W + (size_t)r * K;
  float S = np_pairwise_wave<true>(row, K, lane);
  float s = fmaxf(S / (float)K, 1e-5f);
  if (lane == 0) scOut[r] = s;
  _Float16* dst = qOut + (size_t)r * K;
  for (int k = lane * 4; k < K; k += 256) {
    float4 w = *reinterpret_cast<const float4*>(row + k);
    float wv[4] = {w.x, w.y, w.z, w.w};
    half4v q4;
    #pragma unroll
    for (int j = 0; j < 4; ++j) {
      float q = rintf(wv[j] / s);
      q = fminf(1.f, fmaxf(-1.f, q));
      q4[j] = (_Float16)q;
    }
    *reinterpret_cast<half4v*>(dst + k) = q4;
  }
}

// ===== lambda = clip(expf(mean(lq)-mean(lk)), 0.1, 2.0) =====
__global__ __launch_bounds__(64) void k_lambda(const float* __restrict__ lq,
                                               const float* __restrict__ lk,
                                               float* __restrict__ lam) {
  int lane = threadIdx.x;
  float mq = np_pairwise_wave<false>(lq, 1024, lane) / 1024.0f;
  float mk = np_pairwise_wave<false>(lk, 1024, lane) / 1024.0f;
  if (lane == 0) {
    float l = expf(mq - mk);
    lam[0] = fminf(2.0f, fmaxf(0.1f, l));
  }
}

// ===== layernorm f32->f32 (in==out allowed) =====
__global__ __launch_bounds__(256) void k_layernorm(const float* __restrict__ in,
                                                   const float* __restrict__ g,
                                                   const float* __restrict__ b,
                                                   float* __restrict__ out, int Dd) {
  #pragma clang fp contract(off)
  __shared__ float row[2048];
  __shared__ float sq[2048];
  __shared__ float stat[2];
  int m = blockIdx.x, tid = threadIdx.x;
  const float* src = in + (size_t)m * Dd;
  for (int d = tid; d < Dd; d += 256) row[d] = src[d];
  __syncthreads();
  if (tid < 64) {
    float S = np_pairwise_wave<false>(row, Dd, tid);
    if (tid == 0) stat[0] = S;
  }
  __syncthreads();
  float mean = stat[0] / (float)Dd;
  for (int d = tid; d < Dd; d += 256) { float t = row[d] - mean; sq[d] = t * t; }
  __syncthreads();
  if (tid < 64) {
    float S = np_pairwise_wave<false>(sq, Dd, tid);
    if (tid == 0) stat[1] = S;
  }
  __syncthreads();
  float var = stat[1] / (float)Dd;
  float rs = 1.0f / sqrtf(var + 1e-5f);
  float* dst = out + (size_t)m * Dd;
  for (int d = tid; d < Dd; d += 256) {
    float t = row[d] - mean;
    float u = t * rs;
    float v = u * g[d];
    dst[d] = v + b[d];
  }
}

// ===== layernorm f32 -> fp16 hi/lo split (separate out buffers) =====
__global__ __launch_bounds__(256) void k_layernorm_split(const float* __restrict__ in,
                                                         const float* __restrict__ g,
                                                         const float* __restrict__ b,
                                                         _Float16* __restrict__ oh,
                                                         _Float16* __restrict__ ol, int Dd) {
  #pragma clang fp contract(off)
  __shared__ float row[2048];
  __shared__ float sq[2048];
  __shared__ float stat[2];
  int m = blockIdx.x, tid = threadIdx.x;
  const float* src = in + (size_t)m * Dd;
  for (int d = tid; d < Dd; d += 256) row[d] = src[d];
  __syncthreads();
  if (tid < 64) {
    float S = np_pairwise_wave<false>(row, Dd, tid);
    if (tid == 0) stat[0] = S;
  }
  __syncthreads();
  float mean = stat[0] / (float)Dd;
  for (int d = tid; d < Dd; d += 256) { float t = row[d] - mean; sq[d] = t * t; }
  __syncthreads();
  if (tid < 64) {
    float S = np_pairwise_wave<false>(sq, Dd, tid);
    if (tid == 0) stat[1] = S;
  }
  __syncthreads();
  float var = stat[1] / (float)Dd;
  float rs = 1.0f / sqrtf(var + 1e-5f);
  #pragma unroll 1
  for (int d = tid; d < Dd; d += 256) {
    float t = row[d] - mean;
    float u = t * rs;
    float v = u * g[d];
    float w = v + b[d];
    _Float16 hv = (_Float16)w;
    oh[(size_t)m * Dd + d] = hv;
    ol[(size_t)m * Dd + d] = (_Float16)((w - (float)hv) * 2048.0f);
  }
}

// ===== fused double layernorm: LN(g1,b1) then LN(g2,b2); f32 + fp16-hi out =====
__global__ __launch_bounds__(256) void k_lnln(const float* __restrict__ in,
                                              const float* __restrict__ g1, const float* __restrict__ b1,
                                              const float* __restrict__ g2, const float* __restrict__ b2,
                                              float* __restrict__ outf,
                                              _Float16* __restrict__ outh) {
  #pragma clang fp contract(off)
  __shared__ float row[1024];
  __shared__ float tmp[1024];
  __shared__ float stat[2];
  int m = blockIdx.x, tid = threadIdx.x;
  const float* src = in + (size_t)m * 1024;
  for (int d = tid; d < 1024; d += 256) row[d] = src[d];
  __syncthreads();
  if (tid < 64) { float S = np_pairwise_wave<false>(row, 1024, tid); if (tid == 0) stat[0] = S; }
  __syncthreads();
  float mean = stat[0] / 1024.0f;
  for (int d = tid; d < 1024; d += 256) { float t = row[d] - mean; tmp[d] = t * t; }
  __syncthreads();
  if (tid < 64) { float S = np_pairwise_wave<false>(tmp, 1024, tid); if (tid == 0) stat[1] = S; }
  __syncthreads();
  float rs = 1.0f / sqrtf(stat[1] / 1024.0f + 1e-5f);
  for (int d = tid; d < 1024; d += 256) {
    float t = row[d] - mean;
    float u = t * rs;
    float v = u * g1[d];
    tmp[d] = v + b1[d];
  }
  __syncthreads();
  if (tid < 64) { float S = np_pairwise_wave<false>(tmp, 1024, tid); if (tid == 0) stat[0] = S; }
  __syncthreads();
  float mean2 = stat[0] / 1024.0f;
  for (int d = tid; d < 1024; d += 256) { float t = tmp[d] - mean2; row[d] = t * t; }
  __syncthreads();
  if (tid < 64) { float S = np_pairwise_wave<false>(row, 1024, tid); if (tid == 0) stat[1] = S; }
  __syncthreads();
  float rs2 = 1.0f / sqrtf(stat[1] / 1024.0f + 1e-5f);
  for (int d = tid; d < 1024; d += 256) {
    float t = tmp[d] - mean2;
    float u = t * rs2;
    float v = u * g2[d];
    float w = v + b2[d];
    outf[(size_t)m * 1024 + d] = w;
    outh[(size_t)m * 1024 + d] = (_Float16)w;
  }
}

// ===== MFMA GEMM =====
// EPI: 0 f32, 1 silu->fp16hi, 2 res+, 3 fused final, 5 VT split store (Ch,Ch2)
// XM : 0 dense, 1 gather-in/compact-out, 2 compact-in/scatter-out
// DUAL: hi/lo A; WQ: 1 = prequantized fp16 W, 0 = on-the-fly quant
template<int EPI, int XM, int DUAL, int WQ>
__global__ __launch_bounds__(256) void k_mgemm(
    const _Float16* __restrict__ Agh, const _Float16* __restrict__ Agl, int lda,
    const float* __restrict__ Wf, const _Float16* __restrict__ Wh,
    const float* __restrict__ scf,
    float* __restrict__ Cout, _Float16* __restrict__ Ch, _Float16* __restrict__ Ch2,
    int ldc, int N, int K,
    const float* __restrict__ res, const float* __restrict__ add2,
    const int* __restrict__ offs, const int* __restrict__ tlist,
    const float* __restrict__ topp)
{
  int e = XM ? blockIdx.z : 0;
  int mbase = 0, mcount = M_;
  const float* sc = scf;
  const float* Wfb = Wf;
  if (XM) {
    mbase = offs[e]; mcount = offs[e + 1] - mbase;
    if (!WQ) Wfb = Wf + (size_t)e * N * K;
    sc = scf + (size_t)e * N;
  }
  int m0 = blockIdx.y * 128;
  if (XM && m0 >= mcount) return;
  int n0 = blockIdx.x * 64;

  __shared__ __align__(16) _Float16 As[4][128][8];
  __shared__ __align__(16) _Float16 Als[DUAL ? 4 : 1][128][8];
  __shared__ __align__(16) _Float16 Qs[4][64][8];

  int tid = threadIdx.x;
  int lm  = tid >> 1;
  int kcA = (tid & 1) * 16;
  int lw  = tid >> 2;
  int kcW = (tid & 3) * 8;

  int am  = m0 + lm;
  int amc = XM ? ((am < mcount) ? am : (mcount - 1)) : am;
  int arow;
  if (XM == 1)      arow = tlist[mbase + amc];
  else if (XM == 2) arow = mbase + amc;
  else              arow = am;
  const _Float16* Arh = Agh + (size_t)arow * lda;
  const _Float16* Arl = DUAL ? (Agl + (size_t)arow * lda) : nullptr;
  const float*    Wrf = WQ ? nullptr : (Wfb + (size_t)(n0 + lw) * K);
  const _Float16* Wrh = WQ ? (Wh + (size_t)(n0 + lw) * K) : nullptr;
  float wscale = WQ ? 0.f : sc[n0 + lw];

  int wv = tid >> 6, lane = tid & 63;
  int wm = wv >> 1, wn = wv & 1;
  int ks = lane >> 4, fr = lane & 15;

  f32x4 acch[4][2], accl[4][2];
  #pragma unroll
  for (int i = 0; i < 4; i++)
    #pragma unroll
    for (int j = 0; j < 2; j++) { acch[i][j] = (f32x4)0.f; accl[i][j] = (f32x4)0.f; }

  for (int kt = 0; kt < K; kt += 32) {
    half8 a0 = *reinterpret_cast<const half8*>(Arh + kt + kcA);
    half8 a1 = *reinterpret_cast<const half8*>(Arh + kt + kcA + 8);
    half8 b0, b1;
    if (DUAL) {
      b0 = *reinterpret_cast<const half8*>(Arl + kt + kcA);
      b1 = *reinterpret_cast<const half8*>(Arl + kt + kcA + 8);
    }
    half8 qv;
    if (WQ) {
      qv = *reinterpret_cast<const half8*>(Wrh + kt + kcW);
    } else {
      float4 w0 = *reinterpret_cast<const float4*>(Wrf + kt + kcW);
      float4 w1 = *reinterpret_cast<const float4*>(Wrf + kt + kcW + 4);
      float wvv[8] = {w0.x,w0.y,w0.z,w0.w, w1.x,w1.y,w1.z,w1.w};
      #pragma unroll
      for (int j = 0; j < 8; j++) {
        float qq = rintf(wvv[j] / wscale);
        qq = fminf(1.f, fmaxf(-1.f, qq));
        qv[j] = (_Float16)qq;
      }
    }
    __syncthreads();
    int sA = kcA >> 3;
    *reinterpret_cast<half8*>(&As[sA][lm][0])     = a0;
    *reinterpret_cast<half8*>(&As[sA + 1][lm][0]) = a1;
    if (DUAL) {
      *reinterpret_cast<half8*>(&Als[sA][lm][0])     = b0;
      *reinterpret_cast<half8*>(&Als[sA + 1][lm][0]) = b1;
    }
    *reinterpret_cast<half8*>(&Qs[kcW >> 3][lw][0]) = qv;
    __syncthreads();
    half8 bfr0 = *reinterpret_cast<half8*>(&Qs[ks][wn * 32 + fr][0]);
    half8 bfr1 = *reinterpret_cast<half8*>(&Qs[ks][wn * 32 + 16 + fr][0]);
    #pragma unroll
    for (int i = 0; i < 4; i++) {
      half8 ah = *reinterpret_cast<half8*>(&As[ks][wm * 64 + i * 16 + fr][0]);
      acch[i][0] = __builtin_amdgcn_mfma_f32_16x16x32_f16(ah, bfr0, acch[i][0], 0, 0, 0);
      acch[i][1] = __builtin_amdgcn_mfma_f32_16x16x32_f16(ah, bfr1, acch[i][1], 0, 0, 0);
      if (DUAL) {
        half8 al = *reinterpret_cast<half8*>(&Als[ks][wm * 64 + i * 16 + fr][0]);
        accl[i][0] = __builtin_amdgcn_mfma_f32_16x16x32_f16(al, bfr0, accl[i][0], 0, 0, 0);
        accl[i][1] = __builtin_amdgcn_mfma_f32_16x16x32_f16(al, bfr1, accl[i][1], 0, 0, 0);
      }
    }
  }

  #pragma unroll
  for (int j = 0; j < 2; j++) {
    int col = n0 + wn * 32 + j * 16 + fr;
    float scl = sc[col];
    #pragma unroll
    for (int i = 0; i < 4; i++) {
      #pragma unroll
      for (int r = 0; r < 4; r++) {
        int lrow = m0 + wm * 64 + i * 16 + ks * 4 + r;
        if (XM && lrow >= mcount) continue;
        int orow;
        if (XM == 1)      orow = mbase + lrow;
        else if (XM == 2) orow = tlist[mbase + lrow];
        else              orow = lrow;
        float v = acch[i][j][r];
        if (DUAL) v += accl[i][j][r] * (1.0f / 2048.0f);
        v *= scl;
        if (EPI == 1) {
          v = v * (1.0f / (1.0f + expf(-v)));
          Ch[(size_t)orow * ldc + col] = (_Float16)v;
        } else if (EPI == 3) {
          float rt = v * topp[orow];
          float moe = add2[(size_t)orow * ldc + col] + rt;
          Cout[(size_t)orow * ldc + col] = res[(size_t)orow * ldc + col] + moe;
        } else if (EPI == 5) {
          int bb = orow >> 10, tok = orow & 1023;
          size_t vidx = ((size_t)(bb << 10) + col) * 1024 + tok;
          _Float16 hv = (_Float16)v;
          Ch[vidx] = hv;
          Ch2[vidx] = (_Float16)((v - (float)hv) * 2048.0f);
        } else if (EPI == 2) {
          Cout[(size_t)orow * ldc + col] = res[(size_t)orow * ldc + col] + v;
        } else {
          Cout[(size_t)orow * ldc + col] = v;
        }
      }
    }
  }
}

// ===== MFMA flash differential attention (pre-split K/V, balanced tq map) =====
__global__ __launch_bounds__(256) void k_attn4(const float* __restrict__ q,
                                               const _Float16* __restrict__ khg,
                                               const _Float16* __restrict__ klg,
                                               const _Float16* __restrict__ vth,
                                               const _Float16* __restrict__ vtl,
                                               const float* __restrict__ lamp,
                                               _Float16* __restrict__ aoh,
                                               _Float16* __restrict__ aol)
{
  __shared__ __align__(16) _Float16 KH[2][64][72];
  __shared__ __align__(16) _Float16 KL[2][64][72];
  __shared__ __align__(16) _Float16 VH[64][72];
  __shared__ __align__(16) _Float16 VL[64][72];
  __shared__ __align__(16) _Float16 PH[4][16][72];
  __shared__ __align__(16) _Float16 PL[4][16][72];

  int bh = blockIdx.x;
  int b = bh >> 4, h = bh & 15;
  int y = blockIdx.y;
  int tq = (y < 8) ? (2 * y) : (31 - 2 * y);   // balanced pairing
  int t0 = tq * 64;
  int tid = threadIdx.x;
  int wm = tid >> 6, lane = tid & 63;
  int ks = lane >> 4, fr = lane & 15;
  size_t tokbase = (size_t)b * T_;
  float lam = lamp[0];

  half8 qh[2][2], ql[2][2];
  {
    const float* qr = q + (tokbase + t0 + wm * 16 + fr) * 2048 + h * 64;
    #pragma unroll
    for (int g = 0; g < 2; ++g)
      #pragma unroll
      for (int s = 0; s < 2; ++s) {
        const float* p = qr + g * 1024 + s * 32 + ks * 8;
        float4 x0 = *reinterpret_cast<const float4*>(p);
        float4 x1 = *reinterpret_cast<const float4*>(p + 4);
        float xv[8] = {x0.x,x0.y,x0.z,x0.w, x1.x,x1.y,x1.z,x1.w};
        half8 hh, ll;
        #pragma unroll
        for (int j = 0; j < 8; ++j) {
          _Float16 hv = (_Float16)xv[j];
          hh[j] = hv; ll[j] = (_Float16)((xv[j] - (float)hv) * 2048.0f);
        }
        qh[g][s] = hh; ql[g][s] = ll;
      }
  }

  f32x4 Oh[2][4], Ox[2][4];
  #pragma unroll
  for (int g = 0; g < 2; ++g)
    #pragma unroll
    for (int d = 0; d < 4; ++d) { Oh[g][d] = (f32x4)0.f; Ox[g][d] = (f32x4)0.f; }
  float mrun[2][4], lrun[2][4];
  #pragma unroll
  for (int g = 0; g < 2; ++g)
    #pragma unroll
    for (int r = 0; r < 4; ++r) { mrun[g][r] = -1e30f; lrun[g][r] = 0.f; }

  for (int jt = 0; jt <= tq; ++jt) {
    int kv0 = jt * 64;
    __syncthreads();
    {
      // K staging: pure half8 copies (pre-split by LN)
      int key = tid & 63;
      int d0 = (tid >> 6) * 16;
      #pragma unroll
      for (int g = 0; g < 2; ++g) {
        const _Float16* sh = khg + ((size_t)(tokbase + kv0 + key)) * 2048 + g * 1024 + h * 64 + d0;
        const _Float16* sl = klg + ((size_t)(tokbase + kv0 + key)) * 2048 + g * 1024 + h * 64 + d0;
        *reinterpret_cast<half8*>(&KH[g][key][d0])     = *reinterpret_cast<const half8*>(sh);
        *reinterpret_cast<half8*>(&KH[g][key][d0 + 8]) = *reinterpret_cast<const half8*>(sh + 8);
        *reinterpret_cast<half8*>(&KL[g][key][d0])     = *reinterpret_cast<const half8*>(sl);
        *reinterpret_cast<half8*>(&KL[g][key][d0 + 8]) = *reinterpret_cast<const half8*>(sl + 8);
      }
      // V staging: pure half8 copies (pre-split by Wv epilogue)
      int dd = tid & 63;
      int k0 = (tid >> 6) * 16;
      size_t vb = ((size_t)b * 1024 + h * 64 + dd) * 1024 + kv0 + k0;
      *reinterpret_cast<half8*>(&VH[dd][k0])     = *reinterpret_cast<const half8*>(vth + vb);
      *reinterpret_cast<half8*>(&VH[dd][k0 + 8]) = *reinterpret_cast<const half8*>(vth + vb + 8);
      *reinterpret_cast<half8*>(&VL[dd][k0])     = *reinterpret_cast<const half8*>(vtl + vb);
      *reinterpret_cast<half8*>(&VL[dd][k0 + 8]) = *reinterpret_cast<const half8*>(vtl + vb + 8);
    }
    __syncthreads();

    bool diag = (jt == tq);
    #pragma unroll
    for (int g = 0; g < 2; ++g) {
      f32x4 Sh[4], Sx[4];
      #pragma unroll
      for (int kf = 0; kf < 4; ++kf) { Sh[kf] = (f32x4)0.f; Sx[kf] = (f32x4)0.f; }
      #pragma unroll
      for (int s = 0; s < 2; ++s) {
        #pragma unroll
        for (int kf = 0; kf < 4; ++kf) {
          half8 kh = *reinterpret_cast<half8*>(&KH[g][kf * 16 + fr][s * 32 + ks * 8]);
          half8 kl = *reinterpret_cast<half8*>(&KL[g][kf * 16 + fr][s * 32 + ks * 8]);
          Sh[kf] = __builtin_amdgcn_mfma_f32_16x16x32_f16(qh[g][s], kh, Sh[kf], 0, 0, 0);
          Sx[kf] = __builtin_amdgcn_mfma_f32_16x16x32_f16(qh[g][s], kl, Sx[kf], 0, 0, 0);
          Sx[kf] = __builtin_amdgcn_mfma_f32_16x16x32_f16(ql[g][s], kh, Sx[kf], 0, 0, 0);
        }
      }
      float sv[4][4];
      #pragma unroll
      for (int kf = 0; kf < 4; ++kf)
        #pragma unroll
        for (int r = 0; r < 4; ++r) {
          float s_ = (Sh[kf][r] + Sx[kf][r] * (1.0f / 2048.0f)) * 0.125f;
          if (diag) {
            int row_abs = t0 + wm * 16 + ks * 4 + r;
            int col_abs = kv0 + kf * 16 + fr;
            if (col_abs > row_abs) s_ = -1e30f;
          }
          sv[kf][r] = s_;
        }
      #pragma unroll
      for (int r = 0; r < 4; ++r) {
        float tmax = fmaxf(fmaxf(sv[0][r], sv[1][r]), fmaxf(sv[2][r], sv[3][r]));
        #pragma unroll
        for (int msk = 1; msk < 16; msk <<= 1) tmax = fmaxf(tmax, __shfl_xor(tmax, msk));
        bool up = tmax > mrun[g][r];
        float mnew = up ? tmax : mrun[g][r];
        float e0 = expf(sv[0][r] - mnew);
        float e1 = expf(sv[1][r] - mnew);
        float e2 = expf(sv[2][r] - mnew);
        float e3 = expf(sv[3][r] - mnew);
        float rsum = (e0 + e1) + (e2 + e3);
        #pragma unroll
        for (int msk = 1; msk < 16; msk <<= 1) rsum += __shfl_xor(rsum, msk);
        if (up) {
          float scale = expf(mrun[g][r] - tmax);
          lrun[g][r] = lrun[g][r] * scale + rsum;
          mrun[g][r] = tmax;
          #pragma unroll
          for (int df = 0; df < 4; ++df) { Oh[g][df][r] *= scale; Ox[g][df][r] *= scale; }
        } else {
          lrun[g][r] += rsum;
        }
        float ev[4] = {e0, e1, e2, e3};
        #pragma unroll
        for (int kf = 0; kf < 4; ++kf) {
          _Float16 ph = (_Float16)ev[kf];
          _Float16 pl = (_Float16)((ev[kf] - (float)ph) * 2048.0f);
          PH[wm][ks * 4 + r][kf * 16 + fr] = ph;
          PL[wm][ks * 4 + r][kf * 16 + fr] = pl;
        }
      }
      #pragma unroll
      for (int s = 0; s < 2; ++s) {
        half8 pah = *reinterpret_cast<half8*>(&PH[wm][fr][s * 32 + ks * 8]);
        half8 pal = *reinterpret_cast<half8*>(&PL[wm][fr][s * 32 + ks * 8]);
        #pragma unroll
        for (int df = 0; df < 4; ++df) {
          half8 vh = *reinterpret_cast<half8*>(&VH[df * 16 + fr][s * 32 + ks * 8]);
          half8 vl = *reinterpret_cast<half8*>(&VL[df * 16 + fr][s * 32 + ks * 8]);
          Oh[g][df] = __builtin_amdgcn_mfma_f32_16x16x32_f16(pah, vh, Oh[g][df], 0, 0, 0);
          Ox[g][df] = __builtin_amdgcn_mfma_f32_16x16x32_f16(pah, vl, Ox[g][df], 0, 0, 0);
          Ox[g][df] = __builtin_amdgcn_mfma_f32_16x16x32_f16(pal, vh, Ox[g][df], 0, 0, 0);
        }
      }
    }
  }

  #pragma unroll
  for (int df = 0; df < 4; ++df) {
    #pragma unroll
    for (int r = 0; r < 4; ++r) {
      int row_abs = t0 + wm * 16 + ks * 4 + r;
      int d = df * 16 + fr;
      float o1 = (Oh[0][df][r] + Ox[0][df][r] * (1.0f / 2048.0f)) / lrun[0][r];
      float o2 = (Oh[1][df][r] + Ox[1][df][r] * (1.0f / 2048.0f)) / lrun[1][r];
      float oo = o1 - lam * o2;
      size_t idx = (tokbase + row_abs) * 1024 + h * 64 + d;
      _Float16 hv = (_Float16)oo;
      aoh[idx] = hv;
      aol[idx] = (_Float16)((oo - (float)hv) * 2048.0f);
    }
  }
}

// ===== router =====
__global__ __launch_bounds__(256) void k_router(const float* __restrict__ hm,
                                                const float* __restrict__ rw,
                                                int* __restrict__ idx,
                                                float* __restrict__ topp)
{
  #pragma clang fp contract(off)
  int tid = threadIdx.x;
  int tg = tid >> 3, e = tid & 7;
  int m = blockIdx.x * 32 + tg;
  const float* hr = hm + (size_t)m * 1024;
  const float* wr = rw + (size_t)e * 1024;
  float l = 0.f;
  for (int dd = 0; dd < 1024; ++dd) l = __builtin_fmaf(hr[dd], wr[dd], l);
  float mx = l;
  #pragma unroll
  for (int off = 1; off < 8; off <<= 1) mx = fmaxf(mx, __shfl_xor(mx, off, 8));
  float p = expf(l - mx);
  float den = p;
  #pragma unroll
  for (int off = 1; off < 8; off <<= 1) den += __shfl_xor(den, off, 8);
  float prob = p / den;
  float pm = prob;
  #pragma unroll
  for (int off = 1; off < 8; off <<= 1) pm = fmaxf(pm, __shfl_xor(pm, off, 8));
  unsigned long long ball = __ballot(prob == pm);
  int grp = (tid & 63) >> 3;
  int first = __ffsll((unsigned long long)((ball >> (grp * 8)) & 0xFFull)) - 1;
  if (e == 0) { idx[m] = first; topp[m] = pm; }
}

// ===== deterministic token compaction =====
__global__ __launch_bounds__(512) void k_route_fill(const int* __restrict__ idx,
                                                    int* __restrict__ offs,
                                                    int* __restrict__ tlist)
{
  __shared__ int cnt[8];
  __shared__ int off[9];
  int w = threadIdx.x >> 6, lane = threadIdx.x & 63;
  int total = 0;
  for (int it = 0; it < M_ / 64; ++it) {
    int tok = it * 64 + lane;
    unsigned long long m = __ballot(idx[tok] == w);
    total += __popcll(m);
  }
  if (lane == 0) cnt[w] = total;
  __syncthreads();
  if (threadIdx.x == 0) {
    int o = 0;
    for (int e = 0; e < 8; ++e) { off[e] = o; o += cnt[e]; }
    off[8] = o;
    for (int e = 0; e < 9; ++e) offs[e] = off[e];
  }
  __syncthreads();
  int base = off[w];
  for (int it = 0; it < M_ / 64; ++it) {
    int tok = it * 64 + lane;
    bool sel = (idx[tok] == w);
    unsigned long long m = __ballot(sel);
    if (sel) {
      int pos = base + __popcll(m & ((1ull << lane) - 1ull));
      tlist[pos] = tok;
    }
    base += __popcll(m);
  }
}

extern "C" void kernel_launch(void* const* d_in, const int* in_sizes, int n_in,
                              void* d_out, int out_size, void* d_ws, size_t ws_size,
                              hipStream_t stream) {
  const float* x   = (const float*)d_in[0];
  const float* Wq  = (const float*)d_in[2];
  const float* Wk  = (const float*)d_in[3];
  const float* Wv  = (const float*)d_in[4];
  const float* Wo  = (const float*)d_in[5];
  const float* lq  = (const float*)d_in[6];
  const float* lk  = (const float*)d_in[7];
  const float* qng = (const float*)d_in[8];
  const float* qnb = (const float*)d_in[9];
  const float* kng = (const float*)d_in[10];
  const float* knb = (const float*)d_in[11];
  const float* ag  = (const float*)d_in[12];
  const float* ab  = (const float*)d_in[13];
  const float* fg  = (const float*)d_in[14];
  const float* fb  = (const float*)d_in[15];
  const float* mg  = (const float*)d_in[16];
  const float* mb  = (const float*)d_in[17];
  const float* sw1 = (const float*)d_in[18];
  const float* sw2 = (const float*)d_in[19];
  const float* ew1 = (const float*)d_in[20];
  const float* ew2 = (const float*)d_in[21];
  const float* rw  = (const float*)d_in[22];

  float* ws = (float*)d_ws;
  size_t o = 0;
  float* scWq = ws + o; o += 2048;
  float* scWk = ws + o; o += 2048;
  float* scWv = ws + o; o += 1024;
  float* scWo = ws + o; o += 1024;
  float* scS1 = ws + o; o += 2048;
  float* scS2 = ws + o; o += 1024;
  float* scE1 = ws + o; o += 8 * 2048;
  float* scE2 = ws + o; o += 8 * 1024;
  float* lam  = ws + o; o += 16;
  float* TOPP = ws + o; o += 2048;
  int*   IDX  = (int*)(ws + o); o += 2048;
  int*   OFFS = (int*)(ws + o); o += 16;
  int*   TLIST= (int*)(ws + o); o += 2048;
  o = (o + 15) & ~(size_t)15;

  // pre-quantized fp16 dense weights
  _Float16* QWq = (_Float16*)(ws + o); o += 1024 * 1024;
  _Float16* QWk = (_Float16*)(ws + o); o += 1024 * 1024;
  _Float16* QWv = (_Float16*)(ws + o); o += 512 * 1024;
  _Float16* QWo = (_Float16*)(ws + o); o += 512 * 1024;
  _Float16* QS1 = (_Float16*)(ws + o); o += 1024 * 1024;
  _Float16* QS2 = (_Float16*)(ws + o); o += 1024 * 1024;

  // region A: H1h+H1l -> SMh -> T1h
  float* RA = ws + o; o += 2 * 1024 * 1024;
  _Float16* H1h = (_Float16*)RA;
  _Float16* H1l = (_Float16*)(RA + 1024 * 1024);
  _Float16* SMh = (_Float16*)RA;
  _Float16* T1h = (_Float16*)RA;
  // region B: AOh+AOl -> HMh
  float* RB = ws + o; o += 2 * 1024 * 1024;
  _Float16* AOh = (_Float16*)RB;
  _Float16* AOl = (_Float16*)(RB + 1024 * 1024);
  _Float16* HMh = (_Float16*)RB;

  const size_t MQ = (size_t)M_ * 2048;
  float* QP = ws + o; o += MQ;          // f32 Q (LN in-place) -> X1 | HM after attn
  float* KP = ws + o; o += MQ;          // f32 K (GEMM out)    -> SO after attn
  // pre-split K (fp16 hi/lo, fresh 16MB)
  _Float16* KHg = (_Float16*)(ws + o); o += 2 * 1024 * 1024;
  _Float16* KLg = (_Float16*)(ws + o); o += 2 * 1024 * 1024;
  // pre-split V transposed (fp16 hi/lo, in old VT slot)
  _Float16* VTH = (_Float16*)(ws + o); o += 1024 * 1024;
  _Float16* VTL = (_Float16*)(ws + o); o += 1024 * 1024;

  float* X1 = QP;
  float* HM = QP + MQ / 2;
  float* SO = KP;

  // scales (+ fused prequant for dense) + lambda
  k_scaleq<<<2048, 64, 0, stream>>>(Wq,  1024, scWq, QWq);
  k_scaleq<<<2048, 64, 0, stream>>>(Wk,  1024, scWk, QWk);
  k_scaleq<<<1024, 64, 0, stream>>>(Wv,  1024, scWv, QWv);
  k_scaleq<<<1024, 64, 0, stream>>>(Wo,  1024, scWo, QWo);
  k_scaleq<<<2048, 64, 0, stream>>>(sw1, 1024, scS1, QS1);
  k_scaleq<<<1024, 64, 0, stream>>>(sw2, 2048, scS2, QS2);
  k_scale<<<8 * 2048, 64, 0, stream>>>(ew1, 1024, scE1);
  k_scale<<<8 * 1024, 64, 0, stream>>>(ew2, 2048, scE2);
  k_lambda<<<1, 64, 0, stream>>>(lq, lk, lam);

  // attention block (router path: DUAL, bitwise-identical)
  k_layernorm_split<<<M_, 256, 0, stream>>>(x, ag, ab, H1h, H1l, 1024);
  k_mgemm<0,0,1,1><<<dim3(32,16), 256, 0, stream>>>(H1h, H1l, 1024, nullptr, QWq, scWq, QP, nullptr, nullptr, 2048, 2048, 1024, nullptr, nullptr, nullptr, nullptr, nullptr);
  k_mgemm<0,0,1,1><<<dim3(32,16), 256, 0, stream>>>(H1h, H1l, 1024, nullptr, QWk, scWk, KP, nullptr, nullptr, 2048, 2048, 1024, nullptr, nullptr, nullptr, nullptr, nullptr);
  k_mgemm<5,0,1,1><<<dim3(16,16), 256, 0, stream>>>(H1h, H1l, 1024, nullptr, QWv, scWv, nullptr, VTH, VTL, 1024, 1024, 1024, nullptr, nullptr, nullptr, nullptr, nullptr);
  k_layernorm<<<M_, 256, 0, stream>>>(QP, qng, qnb, QP, 2048);
  k_layernorm_split<<<M_, 256, 0, stream>>>(KP, kng, knb, KHg, KLg, 2048);
  k_attn4<<<dim3(32, 16), 256, 0, stream>>>(QP, KHg, KLg, VTH, VTL, lam, AOh, AOl);
  k_mgemm<2,0,1,1><<<dim3(16,16), 256, 0, stream>>>(AOh, AOl, 1024, nullptr, QWo, scWo, X1, nullptr, nullptr, 1024, 1024, 1024, x, nullptr, nullptr, nullptr, nullptr);

  // MoE block
  k_lnln<<<M_, 256, 0, stream>>>(X1, fg, fb, mg, mb, HM, HMh);
  k_router<<<M_ / 32, 256, 0, stream>>>(HM, rw, IDX, TOPP);
  k_route_fill<<<1, 512, 0, stream>>>(IDX, OFFS, TLIST);

  // shared path (single-pass hi-only)
  k_mgemm<1,0,0,1><<<dim3(32,16), 256, 0, stream>>>(HMh, nullptr, 1024, nullptr, QS1, scS1, nullptr, SMh, nullptr, 2048, 2048, 1024, nullptr, nullptr, nullptr, nullptr, nullptr);
  k_mgemm<0,0,0,1><<<dim3(16,16), 256, 0, stream>>>(SMh, nullptr, 2048, nullptr, QS2, scS2, SO, nullptr, nullptr, 1024, 1024, 2048, nullptr, nullptr, nullptr, nullptr, nullptr);

  // routed experts (sparse top-1, single-pass; final add fused into scatter)
  k_mgemm<1,1,0,0><<<dim3(32,16,8), 256, 0, stream>>>(HMh, nullptr, 1024, ew1, nullptr, scE1, nullptr, T1h, nullptr, 2048, 2048, 1024, nullptr, nullptr, OFFS, TLIST, nullptr);
  k_mgemm<3,2,0,0><<<dim3(16,16,8), 256, 0, stream>>>(T1h, nullptr, 2048, ew2, nullptr, scE2, (float*)d_out, nullptr, nullptr, 1024, 1024, 2048, X1, SO, OFFS, TLIST, TOPP);
}